// Round 4
// baseline (1657.331 us; speedup 1.0000x reference)
//
#include <hip/hip_runtime.h>
#include <math.h>

// Problem constants (fixed by the reference)
#define BATCH 4
#define SEQ   2048
#define EDIM  512
#define NH    8
#define HD    64
#define FFD   2048
#define NLAYER 2
#define MTOK  (BATCH * SEQ)            // 8192 rows
#define MEL   ((long long)MTOK * EDIM) // 4194304 elements per (M,E) buffer

typedef __attribute__((ext_vector_type(8))) short bf16x8;
typedef __attribute__((ext_vector_type(4))) float f32x4;

// ---------------------------------------------------------------------------
// fp32 <-> split-bf16 helpers: a ≈ hi + lo, each bf16 (RNE), ~16 mantissa bits
// ---------------------------------------------------------------------------
__device__ __forceinline__ unsigned short f2bf(float f) {
  unsigned u = __float_as_uint(f);
  u += 0x7fffu + ((u >> 16) & 1u);     // round to nearest even
  return (unsigned short)(u >> 16);
}
__device__ __forceinline__ float bf2f(unsigned short h) {
  return __uint_as_float(((unsigned)h) << 16);
}
__device__ __forceinline__ void splitf(float v, unsigned short* hi, unsigned short* lo) {
  unsigned short h = f2bf(v);
  *hi = h;
  *lo = f2bf(v - bf2f(h));
}

// ---------------------------------------------------------------------------
// Embedding + positional encoding; emits fp32 h (residual) + split-bf16 h2.
// ---------------------------------------------------------------------------
__global__ __launch_bounds__(256) void embed_kernel(
    const int* __restrict__ x, const float* __restrict__ emb,
    const float* __restrict__ pos, float* __restrict__ h,
    unsigned short* __restrict__ h2)
{
  int idx = blockIdx.x * 256 + threadIdx.x;   // over MTOK * (EDIM/4)
  int t = idx >> 7;                           // EDIM/4 = 128 float4 per row
  int c = idx & 127;
  int s = t & (SEQ - 1);
  int v = x[t];
  float4 ev = ((const float4*)emb)[(long long)v * 128 + c];
  float4 pv = ((const float4*)pos)[(long long)s * 128 + c];
  float4 r;
  r.x = ev.x + pv.x; r.y = ev.y + pv.y; r.z = ev.z + pv.z; r.w = ev.w + pv.w;
  ((float4*)h)[idx] = r;

  ushort4 hi, lo;
  splitf(r.x, &hi.x, &lo.x); splitf(r.y, &hi.y, &lo.y);
  splitf(r.z, &hi.z, &lo.z); splitf(r.w, &hi.w, &lo.w);
  size_t base = ((size_t)t << 10) + (size_t)c * 4;   // row stride 2*EDIM=1024
  *(ushort4*)&h2[base] = hi;
  *(ushort4*)&h2[base + EDIM] = lo;
}

// ---------------------------------------------------------------------------
// Generic fp32 (rows x K) -> split-bf16 (rows x 2K, [hi | lo]) converter.
// K = 4<<shift. Used for weights only.
// ---------------------------------------------------------------------------
__global__ __launch_bounds__(256) void split_kernel(
    const float* __restrict__ src, unsigned short* __restrict__ dst, int shift)
{
  int idx = blockIdx.x * 256 + threadIdx.x;
  int row = idx >> shift;
  int c4 = idx & ((1 << shift) - 1);
  int Koff = 4 << shift;
  float4 v = ((const float4*)src)[idx];
  ushort4 hi, lo;
  splitf(v.x, &hi.x, &lo.x); splitf(v.y, &hi.y, &lo.y);
  splitf(v.z, &hi.z, &lo.z); splitf(v.w, &hi.w, &lo.w);
  size_t base = ((size_t)row << (shift + 3)) + (size_t)c4 * 4;  // row stride 2K
  *(ushort4*)&dst[base] = hi;
  *(ushort4*)&dst[base + Koff] = lo;
}

// ---------------------------------------------------------------------------
// Split-bf16 GEMM: C[M x N] = A[M x K] * W[N x K]^T (+bias)(+relu); A,W stored
// as [hi | lo] bf16 rows (stride 2K). Virtual K' = 3K: A_hi*B_hi + A_lo*B_hi
// + A_hi*B_lo (A_lo*B_lo dropped, ~2^-16 relative).
// m97 structure: 128x128 tile, BK=64, 4 waves, mfma_f32_16x16x32_bf16,
// linear LDS, global_load_lds width 16.
// outmode 0: fp32 C;  outmode 1: split-bf16 C (rows [hi N | lo N], stride 2N).
// Both modes offset C by blockIdx.z * czstride (elements); B selected by z.
// ---------------------------------------------------------------------------
__global__ __launch_bounds__(256) void gemm_split(
    const unsigned short* __restrict__ A,
    const unsigned short* __restrict__ B0,
    const unsigned short* __restrict__ B1,
    const unsigned short* __restrict__ B2,
    void* __restrict__ Cbase, long long czstride,
    const float* __restrict__ bias,
    int N, int K, int outmode, int relu)
{
  __shared__ unsigned short As[128 * 64];
  __shared__ unsigned short Bs[128 * 64];

  const int tid = threadIdx.x;
  const int lane = tid & 63;
  const int wid = tid >> 6;           // wave 0..3
  const int wr = wid >> 1, wc = wid & 1;
  const int fl = lane & 15;           // fragment row/col
  const int kg = lane >> 4;           // k-group 0..3
  const int z = blockIdx.z;
  const unsigned short* __restrict__ B = (z == 0) ? B0 : ((z == 1) ? B1 : B2);
  const int brow = blockIdx.y * 128;
  const int bcol = blockIdx.x * 128;
  const int ld = 2 * K;

  f32x4 acc[4][4];
#pragma unroll
  for (int i = 0; i < 4; ++i)
#pragma unroll
    for (int j = 0; j < 4; ++j) acc[i][j] = (f32x4){0.f, 0.f, 0.f, 0.f};

  const int r0 = lane >> 3;
  const int c0 = (lane & 7) * 8;

  for (int kt = 0; kt < 3 * K; kt += 64) {
    const int akt = (kt < 2 * K) ? kt : kt - 2 * K;  // hi, lo, hi
    const int bkt = (kt < K) ? kt : kt - K;          // hi, hi, lo
#pragma unroll
    for (int i = 0; i < 4; ++i) {
      const int chunk = i * 4 + wid;                 // 16 chunks of 8 rows
      const int r = chunk * 8 + r0;
      const unsigned short* ga = A + (size_t)(brow + r) * ld + akt + c0;
      const unsigned short* gb = B + (size_t)(bcol + r) * ld + bkt + c0;
      __builtin_amdgcn_global_load_lds(
          (const __attribute__((address_space(1))) void*)ga,
          (__attribute__((address_space(3))) void*)&As[chunk * 512 + lane * 8],
          16, 0, 0);
      __builtin_amdgcn_global_load_lds(
          (const __attribute__((address_space(1))) void*)gb,
          (__attribute__((address_space(3))) void*)&Bs[chunk * 512 + lane * 8],
          16, 0, 0);
    }
    __syncthreads();   // drains vmcnt -> LDS tile ready
#pragma unroll
    for (int kk = 0; kk < 2; ++kk) {
      bf16x8 av[4], bv[4];
#pragma unroll
      for (int f = 0; f < 4; ++f) {
        av[f] = *(const bf16x8*)&As[(wr * 64 + f * 16 + fl) * 64 + kk * 32 + kg * 8];
        bv[f] = *(const bf16x8*)&Bs[(wc * 64 + f * 16 + fl) * 64 + kk * 32 + kg * 8];
      }
#pragma unroll
      for (int i = 0; i < 4; ++i)
#pragma unroll
        for (int j = 0; j < 4; ++j)
          acc[i][j] = __builtin_amdgcn_mfma_f32_16x16x32_bf16(av[i], bv[j], acc[i][j], 0, 0, 0);
    }
    __syncthreads();   // tile consumed before next stage overwrites
  }

  // epilogue — C/D layout: col = lane&15, row = (lane>>4)*4 + reg  [m89]
  if (outmode == 0) {
    float* C = (float*)Cbase + (size_t)z * czstride;
#pragma unroll
    for (int j = 0; j < 4; ++j) {
      const int col = bcol + wc * 64 + j * 16 + fl;
      const float bb = bias ? bias[col] : 0.f;
#pragma unroll
      for (int i = 0; i < 4; ++i) {
        const int rowb = brow + wr * 64 + i * 16 + kg * 4;
#pragma unroll
        for (int e = 0; e < 4; ++e) {
          float v = acc[i][j][e] + bb;
          if (relu) v = fmaxf(v, 0.f);
          C[(size_t)(rowb + e) * N + col] = v;
        }
      }
    }
  } else {
    unsigned short* C = (unsigned short*)Cbase + (size_t)z * czstride;
#pragma unroll
    for (int j = 0; j < 4; ++j) {
      const int col = bcol + wc * 64 + j * 16 + fl;
      const float bb = bias ? bias[col] : 0.f;
#pragma unroll
      for (int i = 0; i < 4; ++i) {
        const int rowb = brow + wr * 64 + i * 16 + kg * 4;
#pragma unroll
        for (int e = 0; e < 4; ++e) {
          float v = acc[i][j][e] + bb;
          if (relu) v = fmaxf(v, 0.f);
          unsigned short hi, lo;
          splitf(v, &hi, &lo);
          size_t rb = (size_t)(rowb + e) * (2 * (size_t)N);
          C[rb + col] = hi;
          C[rb + N + col] = lo;
        }
      }
    }
  }
}

// ---------------------------------------------------------------------------
// MFMA flash attention v2, split-bf16, GLOBAL-DIRECT K/V (no LDS staging,
// no barriers — K/V per (b,h) is 1MB, L2-resident; m169 lesson).
// Block = 128 q-rows of one (b,h); 4 INDEPENDENT waves x 32 q-rows; KVBLK=32.
// Inputs: q2/k2 split token-major (stride 1024, [hi512|lo512]); v2t split V^T
// [n=h*64+d][hi 8192 tok | lo 8192 tok] (from the swapped V-GEMM).
// Online softmax matches reference: mask==0 -> -1e20, then * 1/sqrt(S).
// Output: split-bf16 into act2. Only LDS use: P hi/lo round-trip
// (wave-exclusive 32-row slab -> no __syncthreads anywhere).
// ---------------------------------------------------------------------------
__global__ __launch_bounds__(256) void attn_mfma(
    const unsigned short* __restrict__ q2,
    const unsigned short* __restrict__ k2,
    const unsigned short* __restrict__ v2t,
    const int* __restrict__ maskg,
    unsigned short* __restrict__ o2)
{
  __shared__ unsigned short Ps[128 * 72];   // [q-row][hi 32 k | lo 32 k | pad]

  const int tid = threadIdx.x;
  const int lane = tid & 63;
  const int wid = tid >> 6;
  const int fl = lane & 15;
  const int kg = lane >> 4;
  const int b = blockIdx.y >> 3, h = blockIdx.y & 7;
  const int hc = h * 64;
  const int q0w = blockIdx.x * 128 + wid * 32;   // this wave's q block
  const float inv_scale = 0.022097086912079608f; // 1/sqrt(2048)
  const size_t bS = (size_t)b * SEQ;

  // hoisted Q fragments (rows q0w+rg*16+fl): halves ARE the bf16 frags
  bf16x8 aq[2][4];   // [rg][hi d0-32, hi d32-64, lo d0-32, lo d32-64]
#pragma unroll
  for (int rg = 0; rg < 2; ++rg) {
    size_t qr = (bS + q0w + rg * 16 + fl) * 1024 + hc + kg * 8;
    aq[rg][0] = *(const bf16x8*)&q2[qr];
    aq[rg][1] = *(const bf16x8*)&q2[qr + 32];
    aq[rg][2] = *(const bf16x8*)&q2[qr + 512];
    aq[rg][3] = *(const bf16x8*)&q2[qr + 544];
  }

  // per-lane K/V fragment base pointers
  const unsigned short* kb0 = k2 + (bS + fl) * 1024 + hc + kg * 8;       // cf=0
  const unsigned short* kb1 = k2 + (bS + 16 + fl) * 1024 + hc + kg * 8;  // cf=1
  const unsigned short* vb[4];
#pragma unroll
  for (int cf = 0; cf < 4; ++cf)
    vb[cf] = v2t + (size_t)(hc + cf * 16 + fl) * 16384 + bS + kg * 8;
  const int* mrow = maskg + bS;

  float m[2][4], l[2][4];
  f32x4 ov[2][4];
#pragma unroll
  for (int rg = 0; rg < 2; ++rg) {
#pragma unroll
    for (int e = 0; e < 4; ++e) { m[rg][e] = -INFINITY; l[rg][e] = 0.f; }
#pragma unroll
    for (int cf = 0; cf < 4; ++cf) ov[rg][cf] = (f32x4){0.f, 0.f, 0.f, 0.f};
  }

  for (int k0 = 0; k0 < SEQ; k0 += 32) {
    // ---- QK^T: 6 virtual chunks (Qhi*Khi, Qlo*Khi, Qhi*Klo), K from global
    f32x4 sc[2][2];
#pragma unroll
    for (int rg = 0; rg < 2; ++rg)
#pragma unroll
      for (int cf = 0; cf < 2; ++cf) sc[rg][cf] = (f32x4){0.f, 0.f, 0.f, 0.f};

    const size_t krow = (size_t)k0 * 1024;
    const int koff[6] = {0, 32, 0, 32, 512, 544};  // hi d0,d32 | (lo A) | lo d0,d32
#pragma unroll
    for (int c = 0; c < 6; ++c) {
      const int asel = (c < 4) ? c : (c - 4);
      bf16x8 bk0 = *(const bf16x8*)(kb0 + krow + koff[c]);
      bf16x8 bk1 = *(const bf16x8*)(kb1 + krow + koff[c]);
      sc[0][0] = __builtin_amdgcn_mfma_f32_16x16x32_bf16(aq[0][asel], bk0, sc[0][0], 0, 0, 0);
      sc[1][0] = __builtin_amdgcn_mfma_f32_16x16x32_bf16(aq[1][asel], bk0, sc[1][0], 0, 0, 0);
      sc[0][1] = __builtin_amdgcn_mfma_f32_16x16x32_bf16(aq[0][asel], bk1, sc[0][1], 0, 0, 0);
      sc[1][1] = __builtin_amdgcn_mfma_f32_16x16x32_bf16(aq[1][asel], bk1, sc[1][1], 0, 0, 0);
    }

    // ---- mask + scale + online softmax (lane rows = kg*4+e) ----
    const bool dead0 = (mrow[k0 + fl] == 0);
    const bool dead1 = (mrow[k0 + 16 + fl] == 0);
#pragma unroll
    for (int rg = 0; rg < 2; ++rg) {
#pragma unroll
      for (int e = 0; e < 4; ++e) {
        float s0 = dead0 ? -1e20f : sc[rg][0][e];
        float s1 = dead1 ? -1e20f : sc[rg][1][e];
        sc[rg][0][e] = s0 * inv_scale;
        sc[rg][1][e] = s1 * inv_scale;
      }
#pragma unroll
      for (int e = 0; e < 4; ++e) {
        float rm = fmaxf(sc[rg][0][e], sc[rg][1][e]);
        rm = fmaxf(rm, __shfl_xor(rm, 1));
        rm = fmaxf(rm, __shfl_xor(rm, 2));
        rm = fmaxf(rm, __shfl_xor(rm, 4));
        rm = fmaxf(rm, __shfl_xor(rm, 8));
        float mnew = fmaxf(m[rg][e], rm);
        float corr = __expf(m[rg][e] - mnew);   // first tile: exp(-inf)=0
        float p0 = __expf(sc[rg][0][e] - mnew);
        float p1 = __expf(sc[rg][1][e] - mnew);
        sc[rg][0][e] = p0; sc[rg][1][e] = p1;
        float ps = p0 + p1;
        ps += __shfl_xor(ps, 1); ps += __shfl_xor(ps, 2);
        ps += __shfl_xor(ps, 4); ps += __shfl_xor(ps, 8);
        l[rg][e] = l[rg][e] * corr + ps;
        m[rg][e] = mnew;
#pragma unroll
        for (int cf = 0; cf < 4; ++cf) ov[rg][cf][e] *= corr;
      }
      // split P -> LDS (wave-exclusive rows; same-wave RAW, no barrier)
#pragma unroll
      for (int cf = 0; cf < 2; ++cf)
#pragma unroll
        for (int e = 0; e < 4; ++e) {
          float p = sc[rg][cf][e];
          unsigned short phi = f2bf(p);
          unsigned short plo = f2bf(p - bf2f(phi));
          int prow = wid * 32 + rg * 16 + kg * 4 + e;
          Ps[prow * 72 + cf * 16 + fl] = phi;
          Ps[prow * 72 + 32 + cf * 16 + fl] = plo;
        }
    }

    // ---- O += P @ V: 3 chunks (Phi*Vhi, Plo*Vhi, Phi*Vlo), V from global
    const int pko[3] = {0, 32, 0};
    const int vco[3] = {0, 0, 8192};
#pragma unroll
    for (int c = 0; c < 3; ++c) {
      bf16x8 ap0 = *(const bf16x8*)&Ps[(wid * 32 + fl) * 72 + pko[c] + kg * 8];
      bf16x8 ap1 = *(const bf16x8*)&Ps[(wid * 32 + 16 + fl) * 72 + pko[c] + kg * 8];
#pragma unroll
      for (int cf = 0; cf < 4; ++cf) {
        bf16x8 bv = *(const bf16x8*)(vb[cf] + k0 + vco[c]);
        ov[0][cf] = __builtin_amdgcn_mfma_f32_16x16x32_bf16(ap0, bv, ov[0][cf], 0, 0, 0);
        ov[1][cf] = __builtin_amdgcn_mfma_f32_16x16x32_bf16(ap1, bv, ov[1][cf], 0, 0, 0);
      }
    }
  }

  // ---- epilogue: O/l -> split-bf16 into act2 ----
#pragma unroll
  for (int rg = 0; rg < 2; ++rg)
#pragma unroll
    for (int e = 0; e < 4; ++e) {
      float inv = 1.0f / l[rg][e];
      size_t trow = (bS + q0w + rg * 16 + kg * 4 + e) * 1024 + hc;
#pragma unroll
      for (int cf = 0; cf < 4; ++cf) {
        float v = ov[rg][cf][e] * inv;
        unsigned short hi = f2bf(v);
        unsigned short lo = f2bf(v - bf2f(hi));
        o2[trow + cf * 16 + fl] = hi;
        o2[trow + 512 + cf * 16 + fl] = lo;
      }
    }
}

// ---------------------------------------------------------------------------
// Fused residual + LayerNorm: out = LN(X + R) * g + b; optionally emits
// split-bf16 copy (out2, row stride 2*EDIM).
// ---------------------------------------------------------------------------
__global__ __launch_bounds__(128) void ln_res_kernel(
    const float* __restrict__ X, const float* __restrict__ R,
    const float* __restrict__ g, const float* __restrict__ be,
    float* __restrict__ out, unsigned short* __restrict__ out2)
{
  const int row = blockIdx.x;
  const int tid = threadIdx.x;
  const long long off = (long long)row * EDIM + tid * 4;
  float4 xv = *(const float4*)&X[off];
  float4 rv = *(const float4*)&R[off];
  float x0 = xv.x + rv.x, x1 = xv.y + rv.y, x2 = xv.z + rv.z, x3 = xv.w + rv.w;

  __shared__ float red[2];
  float s = (x0 + x1) + (x2 + x3);
#pragma unroll
  for (int o2 = 1; o2 < 64; o2 <<= 1) s += __shfl_xor(s, o2);
  if ((tid & 63) == 0) red[tid >> 6] = s;
  __syncthreads();
  float mean = (red[0] + red[1]) * (1.0f / EDIM);

  float d0 = x0 - mean, d1 = x1 - mean, d2 = x2 - mean, d3 = x3 - mean;
  float s2 = (d0 * d0 + d1 * d1) + (d2 * d2 + d3 * d3);
#pragma unroll
  for (int o2 = 1; o2 < 64; o2 <<= 1) s2 += __shfl_xor(s2, o2);
  __syncthreads();
  if ((tid & 63) == 0) red[tid >> 6] = s2;
  __syncthreads();
  float var = (red[0] + red[1]) * (1.0f / EDIM);
  float rstd = rsqrtf(var + 1e-5f);

  float4 gv = *(const float4*)&g[tid * 4];
  float4 bv = *(const float4*)&be[tid * 4];
  float4 ov;
  ov.x = d0 * rstd * gv.x + bv.x;
  ov.y = d1 * rstd * gv.y + bv.y;
  ov.z = d2 * rstd * gv.z + bv.z;
  ov.w = d3 * rstd * gv.w + bv.w;
  *(float4*)&out[off] = ov;

  if (out2) {
    ushort4 hi, lo;
    splitf(ov.x, &hi.x, &lo.x); splitf(ov.y, &hi.y, &lo.y);
    splitf(ov.z, &hi.z, &lo.z); splitf(ov.w, &hi.w, &lo.w);
    size_t b2 = ((size_t)row << 10) + (size_t)tid * 4;
    *(ushort4*)&out2[b2] = hi;
    *(ushort4*)&out2[b2 + EDIM] = lo;
  }
}

// ---------------------------------------------------------------------------
extern "C" void kernel_launch(void* const* d_in, const int* in_sizes, int n_in,
                              void* d_out, int out_size, void* d_ws, size_t ws_size,
                              hipStream_t stream) {
  (void)in_sizes; (void)n_in; (void)out_size; (void)ws_size;

  const int*   x    = (const int*)d_in[0];
  const int*   mask = (const int*)d_in[1];
  const float* emb  = (const float*)d_in[2];
  const float* pos  = (const float*)d_in[3];
  const float* Wq   = (const float*)d_in[4];
  const float* Wk   = (const float*)d_in[5];
  const float* Wv   = (const float*)d_in[6];
  const float* Wo   = (const float*)d_in[7];
  const float* bo   = (const float*)d_in[8];
  const float* ln1g = (const float*)d_in[9];
  const float* ln1b = (const float*)d_in[10];
  const float* ln2g = (const float*)d_in[11];
  const float* ln2b = (const float*)d_in[12];
  const float* Wf1  = (const float*)d_in[13];
  const float* bf1  = (const float*)d_in[14];
  const float* Wf2  = (const float*)d_in[15];
  const float* bf2  = (const float*)d_in[16];
  float* out = (float*)d_out;

  // ws layout:
  //   hb (MEL f32) | h1 (MEL f32) | region (4*MEL f32 = 67MB):
  //     during attn: q2 [2MEL,3MEL) + k2 [3,4) + v2t [4,5)  [split bf16]
  //     after attn:  t1 (fp32 M x E) aliases q2; later ff2 (bf16 M x 4096)
  //   act2 (M x 1024 bf16) | weight splits
  float* hb = (float*)d_ws;
  float* h1 = hb + MEL;
  unsigned short* q2  = (unsigned short*)(hb + 2 * MEL);
  unsigned short* k2  = q2 + (size_t)MTOK * 1024;
  unsigned short* v2t = k2 + (size_t)MTOK * 1024;   // [512 n][hi 8192 | lo 8192]
  float* t1 = (float*)(hb + 2 * MEL);               // alias q2 (dead post-attn)
  unsigned short* ff2 = (unsigned short*)(hb + 2 * MEL);  // alias whole region
  unsigned short* act2 = (unsigned short*)(hb + 6 * MEL); // M x 1024
  unsigned short* wq2  = act2 + (size_t)MTOK * 1024;      // 512 x 1024 each
  unsigned short* wk2  = wq2 + 512 * 1024;
  unsigned short* wv2  = wk2 + 512 * 1024;
  unsigned short* wo2  = wv2 + 512 * 1024;
  unsigned short* wf12 = wo2 + 512 * 1024;                // 2048 x 1024
  unsigned short* wf22 = wf12 + (size_t)2048 * 1024;      // 512 x 4096

  embed_kernel<<<dim3(MTOK * (EDIM / 4) / 256), 256, 0, stream>>>(x, emb, pos, hb, act2);

  for (int l = 0; l < NLAYER; ++l) {
    const float* wq = Wq + (long long)l * EDIM * EDIM;
    const float* wk = Wk + (long long)l * EDIM * EDIM;
    const float* wv = Wv + (long long)l * EDIM * EDIM;
    const float* wo = Wo + (long long)l * EDIM * EDIM;
    const float* wf1 = Wf1 + (long long)l * FFD * EDIM;
    const float* wf2 = Wf2 + (long long)l * EDIM * FFD;

    // weight hi/lo splits
    split_kernel<<<dim3(256), 256, 0, stream>>>(wq, wq2, 7);      // 512 x 512
    split_kernel<<<dim3(256), 256, 0, stream>>>(wk, wk2, 7);
    split_kernel<<<dim3(256), 256, 0, stream>>>(wv, wv2, 7);
    split_kernel<<<dim3(256), 256, 0, stream>>>(wo, wo2, 7);
    split_kernel<<<dim3(1024), 256, 0, stream>>>(wf1, wf12, 7);   // 2048 x 512
    split_kernel<<<dim3(1024), 256, 0, stream>>>(wf2, wf22, 9);   // 512 x 2048

    // Q,K projections (fused via grid.z), split-bf16 out token-major
    gemm_split<<<dim3(EDIM / 128, MTOK / 128, 2), 256, 0, stream>>>(
        act2, wq2, wk2, nullptr, q2, (long long)MTOK * 1024, nullptr,
        EDIM, EDIM, 1, 0);

    // V projection with SWAPPED operands -> V^T directly: C[n][token]
    gemm_split<<<dim3(MTOK / 128, EDIM / 128, 1), 256, 0, stream>>>(
        wv2, act2, nullptr, nullptr, v2t, 0, nullptr,
        MTOK, EDIM, 1, 0);

    // flash attention v2 (MFMA, global-direct K/V), writes act2 split
    attn_mfma<<<dim3(SEQ / 128, BATCH * NH), 256, 0, stream>>>(
        q2, k2, v2t, mask, act2);

    // output projection (+bo), fp32 out
    gemm_split<<<dim3(EDIM / 128, MTOK / 128, 1), 256, 0, stream>>>(
        act2, wo2, nullptr, nullptr, t1, 0, bo + (long long)l * EDIM,
        EDIM, EDIM, 0, 0);

    // h1 = LN(t1 + h), emit split-bf16 h1 for FFN
    ln_res_kernel<<<MTOK, 128, 0, stream>>>(
        t1, hb, ln1g + (long long)l * EDIM, ln1b + (long long)l * EDIM, h1, act2);

    // ff = relu(h1 @ Wf1^T + bf1), split-bf16 out
    gemm_split<<<dim3(FFD / 128, MTOK / 128, 1), 256, 0, stream>>>(
        act2, wf12, nullptr, nullptr, ff2, 0, bf1 + (long long)l * FFD,
        FFD, EDIM, 1, 1);

    // ff @ Wf2^T + bf2, fp32 out -> hb (old h dead after LN1)
    gemm_split<<<dim3(EDIM / 128, MTOK / 128, 1), 256, 0, stream>>>(
        ff2, wf22, nullptr, nullptr, hb, 0, bf2 + (long long)l * EDIM,
        EDIM, FFD, 0, 0);

    // h = LN(hb + h1); final layer -> d_out
    float* lnout = (l == NLAYER - 1) ? out : hb;
    unsigned short* lnout2 = (l == NLAYER - 1) ? nullptr : act2;
    ln_res_kernel<<<MTOK, 128, 0, stream>>>(
        hb, h1, ln2g + (long long)l * EDIM, ln2b + (long long)l * EDIM, lnout, lnout2);
  }
}

// Round 6
// 1460.603 us; speedup vs baseline: 1.1347x; 1.1347x over previous
//
#include <hip/hip_runtime.h>
#include <math.h>

// Problem constants (fixed by the reference)
#define BATCH 4
#define SEQ   2048
#define EDIM  512
#define NH    8
#define HD    64
#define FFD   2048
#define NLAYER 2
#define MTOK  (BATCH * SEQ)            // 8192 rows
#define MEL   ((long long)MTOK * EDIM) // 4194304 elements per (M,E) buffer

typedef __attribute__((ext_vector_type(8))) short bf16x8;
typedef __attribute__((ext_vector_type(4))) float f32x4;

// ---------------------------------------------------------------------------
// fp32 <-> split-bf16 helpers: a ≈ hi + lo, each bf16 (RNE), ~16 mantissa bits
// ---------------------------------------------------------------------------
__device__ __forceinline__ unsigned short f2bf(float f) {
  unsigned u = __float_as_uint(f);
  u += 0x7fffu + ((u >> 16) & 1u);     // round to nearest even
  return (unsigned short)(u >> 16);
}
__device__ __forceinline__ float bf2f(unsigned short h) {
  return __uint_as_float(((unsigned)h) << 16);
}
__device__ __forceinline__ void splitf(float v, unsigned short* hi, unsigned short* lo) {
  unsigned short h = f2bf(v);
  *hi = h;
  *lo = f2bf(v - bf2f(h));
}

// ---------------------------------------------------------------------------
// Embedding + positional encoding; emits fp32 h (residual) + split-bf16 h2.
// ---------------------------------------------------------------------------
__global__ __launch_bounds__(256) void embed_kernel(
    const int* __restrict__ x, const float* __restrict__ emb,
    const float* __restrict__ pos, float* __restrict__ h,
    unsigned short* __restrict__ h2)
{
  int idx = blockIdx.x * 256 + threadIdx.x;   // over MTOK * (EDIM/4)
  int t = idx >> 7;                           // EDIM/4 = 128 float4 per row
  int c = idx & 127;
  int s = t & (SEQ - 1);
  int v = x[t];
  float4 ev = ((const float4*)emb)[(long long)v * 128 + c];
  float4 pv = ((const float4*)pos)[(long long)s * 128 + c];
  float4 r;
  r.x = ev.x + pv.x; r.y = ev.y + pv.y; r.z = ev.z + pv.z; r.w = ev.w + pv.w;
  ((float4*)h)[idx] = r;

  ushort4 hi, lo;
  splitf(r.x, &hi.x, &lo.x); splitf(r.y, &hi.y, &lo.y);
  splitf(r.z, &hi.z, &lo.z); splitf(r.w, &hi.w, &lo.w);
  size_t base = ((size_t)t << 10) + (size_t)c * 4;   // row stride 2*EDIM=1024
  *(ushort4*)&h2[base] = hi;
  *(ushort4*)&h2[base + EDIM] = lo;
}

// ---------------------------------------------------------------------------
// Generic fp32 (rows x K) -> split-bf16 (rows x 2K, [hi | lo]) converter.
// K = 4<<shift. Used for weights only.
// ---------------------------------------------------------------------------
__global__ __launch_bounds__(256) void split_kernel(
    const float* __restrict__ src, unsigned short* __restrict__ dst, int shift)
{
  int idx = blockIdx.x * 256 + threadIdx.x;
  int row = idx >> shift;
  int c4 = idx & ((1 << shift) - 1);
  int Koff = 4 << shift;
  float4 v = ((const float4*)src)[idx];
  ushort4 hi, lo;
  splitf(v.x, &hi.x, &lo.x); splitf(v.y, &hi.y, &lo.y);
  splitf(v.z, &hi.z, &lo.z); splitf(v.w, &hi.w, &lo.w);
  size_t base = ((size_t)row << (shift + 3)) + (size_t)c4 * 4;  // row stride 2K
  *(ushort4*)&dst[base] = hi;
  *(ushort4*)&dst[base + Koff] = lo;
}

// ---------------------------------------------------------------------------
// Split-bf16 GEMM: C[M x N] = A[M x K] * W[N x K]^T (+bias)(+relu); A,W stored
// as [hi | lo] bf16 rows (stride 2K). Virtual K' = 3K: A_hi*B_hi + A_lo*B_hi
// + A_hi*B_lo (A_lo*B_lo dropped, ~2^-16 relative).
// m97 structure: 128x128 tile, BK=64, 4 waves, mfma_f32_16x16x32_bf16,
// linear LDS, global_load_lds width 16.
// outmode 0: fp32 C;  outmode 1: split-bf16 C (rows [hi N | lo N], stride 2N).
// Both modes offset C by blockIdx.z * czstride (elements); B selected by z.
// ---------------------------------------------------------------------------
__global__ __launch_bounds__(256) void gemm_split(
    const unsigned short* __restrict__ A,
    const unsigned short* __restrict__ B0,
    const unsigned short* __restrict__ B1,
    const unsigned short* __restrict__ B2,
    void* __restrict__ Cbase, long long czstride,
    const float* __restrict__ bias,
    int N, int K, int outmode, int relu)
{
  __shared__ unsigned short As[128 * 64];
  __shared__ unsigned short Bs[128 * 64];

  const int tid = threadIdx.x;
  const int lane = tid & 63;
  const int wid = tid >> 6;           // wave 0..3
  const int wr = wid >> 1, wc = wid & 1;
  const int fl = lane & 15;           // fragment row/col
  const int kg = lane >> 4;           // k-group 0..3
  const int z = blockIdx.z;
  const unsigned short* __restrict__ B = (z == 0) ? B0 : ((z == 1) ? B1 : B2);
  const int brow = blockIdx.y * 128;
  const int bcol = blockIdx.x * 128;
  const int ld = 2 * K;

  f32x4 acc[4][4];
#pragma unroll
  for (int i = 0; i < 4; ++i)
#pragma unroll
    for (int j = 0; j < 4; ++j) acc[i][j] = (f32x4){0.f, 0.f, 0.f, 0.f};

  const int r0 = lane >> 3;
  const int c0 = (lane & 7) * 8;

  for (int kt = 0; kt < 3 * K; kt += 64) {
    const int akt = (kt < 2 * K) ? kt : kt - 2 * K;  // hi, lo, hi
    const int bkt = (kt < K) ? kt : kt - K;          // hi, hi, lo
#pragma unroll
    for (int i = 0; i < 4; ++i) {
      const int chunk = i * 4 + wid;                 // 16 chunks of 8 rows
      const int r = chunk * 8 + r0;
      const unsigned short* ga = A + (size_t)(brow + r) * ld + akt + c0;
      const unsigned short* gb = B + (size_t)(bcol + r) * ld + bkt + c0;
      __builtin_amdgcn_global_load_lds(
          (const __attribute__((address_space(1))) void*)ga,
          (__attribute__((address_space(3))) void*)&As[chunk * 512 + lane * 8],
          16, 0, 0);
      __builtin_amdgcn_global_load_lds(
          (const __attribute__((address_space(1))) void*)gb,
          (__attribute__((address_space(3))) void*)&Bs[chunk * 512 + lane * 8],
          16, 0, 0);
    }
    __syncthreads();   // drains vmcnt -> LDS tile ready
#pragma unroll
    for (int kk = 0; kk < 2; ++kk) {
      bf16x8 av[4], bv[4];
#pragma unroll
      for (int f = 0; f < 4; ++f) {
        av[f] = *(const bf16x8*)&As[(wr * 64 + f * 16 + fl) * 64 + kk * 32 + kg * 8];
        bv[f] = *(const bf16x8*)&Bs[(wc * 64 + f * 16 + fl) * 64 + kk * 32 + kg * 8];
      }
#pragma unroll
      for (int i = 0; i < 4; ++i)
#pragma unroll
        for (int j = 0; j < 4; ++j)
          acc[i][j] = __builtin_amdgcn_mfma_f32_16x16x32_bf16(av[i], bv[j], acc[i][j], 0, 0, 0);
    }
    __syncthreads();   // tile consumed before next stage overwrites
  }

  // epilogue — C/D layout: col = lane&15, row = (lane>>4)*4 + reg  [m89]
  if (outmode == 0) {
    float* C = (float*)Cbase + (size_t)z * czstride;
#pragma unroll
    for (int j = 0; j < 4; ++j) {
      const int col = bcol + wc * 64 + j * 16 + fl;
      const float bb = bias ? bias[col] : 0.f;
#pragma unroll
      for (int i = 0; i < 4; ++i) {
        const int rowb = brow + wr * 64 + i * 16 + kg * 4;
#pragma unroll
        for (int e = 0; e < 4; ++e) {
          float v = acc[i][j][e] + bb;
          if (relu) v = fmaxf(v, 0.f);
          C[(size_t)(rowb + e) * N + col] = v;
        }
      }
    }
  } else {
    unsigned short* C = (unsigned short*)Cbase + (size_t)z * czstride;
#pragma unroll
    for (int j = 0; j < 4; ++j) {
      const int col = bcol + wc * 64 + j * 16 + fl;
      const float bb = bias ? bias[col] : 0.f;
#pragma unroll
      for (int i = 0; i < 4; ++i) {
        const int rowb = brow + wr * 64 + i * 16 + kg * 4;
#pragma unroll
        for (int e = 0; e < 4; ++e) {
          float v = acc[i][j][e] + bb;
          if (relu) v = fmaxf(v, 0.f);
          unsigned short hi, lo;
          splitf(v, &hi, &lo);
          size_t rb = (size_t)(rowb + e) * (2 * (size_t)N);
          C[rb + col] = hi;
          C[rb + N + col] = lo;
        }
      }
    }
  }
}

// ---------------------------------------------------------------------------
// MFMA flash attention v3: global-direct K/V + T14 REGISTER PREFETCH.
// Round-4 PMC: MfmaUtil 10.3%, VALUBusy 27%, HBM 4.8%, Occ 21% (grid-limited
// 2 blk/CU) -> latency-bound on the serial load->MFMA chain. Fix: K frags
// double-buffered (prefetch tile t+1 during tile t, ~1 tile of cover); V
// frags issued at tile top (~300cy cover under QK+softmax). Unrolled x2 with
// named A/B buffers (no runtime-indexed reg arrays). Unique frags/tile: 8 K +
// 8 V bf16x8 (chunks reuse frags). No barriers: 4 independent waves; only LDS
// use is the wave-exclusive P hi/lo round-trip.
// Tail prefetch reads <=32 rows past k2 end -> lands in v2t (valid ws), unused.
// ---------------------------------------------------------------------------
__global__ __launch_bounds__(256, 2) void attn_mfma(
    const unsigned short* __restrict__ q2,
    const unsigned short* __restrict__ k2,
    const unsigned short* __restrict__ v2t,
    const int* __restrict__ maskg,
    unsigned short* __restrict__ o2)
{
  __shared__ unsigned short Ps[128 * 72];   // [q-row][hi 32 k | lo 32 k | pad]

  const int tid = threadIdx.x;
  const int lane = tid & 63;
  const int wid = tid >> 6;
  const int fl = lane & 15;
  const int kg = lane >> 4;
  const int b = blockIdx.y >> 3, h = blockIdx.y & 7;
  const int hc = h * 64;
  const int q0w = blockIdx.x * 128 + wid * 32;   // this wave's q block
  const float inv_scale = 0.022097086912079608f; // 1/sqrt(2048)
  const size_t bS = (size_t)b * SEQ;

  // hoisted Q fragments (rows q0w+rg*16+fl): halves ARE the bf16 frags
  bf16x8 aq[2][4];   // [rg][hi d0-32, hi d32-64, lo d0-32, lo d32-64]
#pragma unroll
  for (int rg = 0; rg < 2; ++rg) {
    size_t qr = (bS + q0w + rg * 16 + fl) * 1024 + hc + kg * 8;
    aq[rg][0] = *(const bf16x8*)&q2[qr];
    aq[rg][1] = *(const bf16x8*)&q2[qr + 32];
    aq[rg][2] = *(const bf16x8*)&q2[qr + 512];
    aq[rg][3] = *(const bf16x8*)&q2[qr + 544];
  }

  // per-lane K/V fragment base pointers
  const unsigned short* kp0 = k2 + (bS + fl) * 1024 + hc + kg * 8;       // cf=0
  const unsigned short* kp1 = k2 + (bS + 16 + fl) * 1024 + hc + kg * 8;  // cf=1
  const unsigned short* vbp[4];
#pragma unroll
  for (int cf = 0; cf < 4; ++cf)
    vbp[cf] = v2t + (size_t)(hc + cf * 16 + fl) * 16384 + bS + kg * 8;
  const int* mrow = maskg + bS;

  float m[2][4], l[2][4];
  f32x4 ov[2][4];
#pragma unroll
  for (int rg = 0; rg < 2; ++rg) {
#pragma unroll
    for (int e = 0; e < 4; ++e) { m[rg][e] = -INFINITY; l[rg][e] = 0.f; }
#pragma unroll
    for (int cf = 0; cf < 4; ++cf) ov[rg][cf] = (f32x4){0.f, 0.f, 0.f, 0.f};
  }

  // unique K frags per tile: {hi d0, hi d32, lo d0, lo d32} x {row grp 0,1}
  auto ldk = [&](bf16x8 (&kf)[8], int k0) {
    size_t kr = (size_t)k0 * 1024;
    kf[0] = *(const bf16x8*)(kp0 + kr);
    kf[1] = *(const bf16x8*)(kp0 + kr + 32);
    kf[2] = *(const bf16x8*)(kp0 + kr + 512);
    kf[3] = *(const bf16x8*)(kp0 + kr + 544);
    kf[4] = *(const bf16x8*)(kp1 + kr);
    kf[5] = *(const bf16x8*)(kp1 + kr + 32);
    kf[6] = *(const bf16x8*)(kp1 + kr + 512);
    kf[7] = *(const bf16x8*)(kp1 + kr + 544);
  };
  // unique V frags per tile: {hi, lo} x 4 cf
  auto ldv = [&](bf16x8 (&vf)[8], int k0) {
#pragma unroll
    for (int cf = 0; cf < 4; ++cf) {
      vf[cf]     = *(const bf16x8*)(vbp[cf] + k0);
      vf[4 + cf] = *(const bf16x8*)(vbp[cf] + k0 + 8192);
    }
  };

  auto tile = [&](const bf16x8 (&kf)[8], const bf16x8 (&vf)[8], int k0) {
    const bool dead0 = (mrow[k0 + fl] == 0);
    const bool dead1 = (mrow[k0 + 16 + fl] == 0);

    // ---- QK^T: 6 virtual chunks; frag reuse via (asel, kidx) pairs ----
    f32x4 sc[2][2];
#pragma unroll
    for (int rg = 0; rg < 2; ++rg)
#pragma unroll
      for (int cf = 0; cf < 2; ++cf) sc[rg][cf] = (f32x4){0.f, 0.f, 0.f, 0.f};

    const int AS[6] = {0, 1, 2, 3, 0, 1};   // Q frag select
    const int KI[6] = {0, 1, 0, 1, 2, 3};   // K frag select
#pragma unroll
    for (int c = 0; c < 6; ++c) {
      sc[0][0] = __builtin_amdgcn_mfma_f32_16x16x32_bf16(aq[0][AS[c]], kf[KI[c]], sc[0][0], 0, 0, 0);
      sc[1][0] = __builtin_amdgcn_mfma_f32_16x16x32_bf16(aq[1][AS[c]], kf[KI[c]], sc[1][0], 0, 0, 0);
      sc[0][1] = __builtin_amdgcn_mfma_f32_16x16x32_bf16(aq[0][AS[c]], kf[4 + KI[c]], sc[0][1], 0, 0, 0);
      sc[1][1] = __builtin_amdgcn_mfma_f32_16x16x32_bf16(aq[1][AS[c]], kf[4 + KI[c]], sc[1][1], 0, 0, 0);
    }

    // ---- mask + scale + online softmax (lane rows = kg*4+e) ----
#pragma unroll
    for (int rg = 0; rg < 2; ++rg) {
#pragma unroll
      for (int e = 0; e < 4; ++e) {
        float s0 = dead0 ? -1e20f : sc[rg][0][e];
        float s1 = dead1 ? -1e20f : sc[rg][1][e];
        sc[rg][0][e] = s0 * inv_scale;
        sc[rg][1][e] = s1 * inv_scale;
      }
#pragma unroll
      for (int e = 0; e < 4; ++e) {
        float rm = fmaxf(sc[rg][0][e], sc[rg][1][e]);
        rm = fmaxf(rm, __shfl_xor(rm, 1));
        rm = fmaxf(rm, __shfl_xor(rm, 2));
        rm = fmaxf(rm, __shfl_xor(rm, 4));
        rm = fmaxf(rm, __shfl_xor(rm, 8));
        float mnew = fmaxf(m[rg][e], rm);
        float corr = __expf(m[rg][e] - mnew);   // first tile: exp(-inf)=0
        float p0 = __expf(sc[rg][0][e] - mnew);
        float p1 = __expf(sc[rg][1][e] - mnew);
        sc[rg][0][e] = p0; sc[rg][1][e] = p1;
        float ps = p0 + p1;
        ps += __shfl_xor(ps, 1); ps += __shfl_xor(ps, 2);
        ps += __shfl_xor(ps, 4); ps += __shfl_xor(ps, 8);
        l[rg][e] = l[rg][e] * corr + ps;
        m[rg][e] = mnew;
#pragma unroll
        for (int cf = 0; cf < 4; ++cf) ov[rg][cf][e] *= corr;
      }
      // split P -> LDS (wave-exclusive rows; same-wave RAW, no barrier)
#pragma unroll
      for (int cf = 0; cf < 2; ++cf)
#pragma unroll
        for (int e = 0; e < 4; ++e) {
          float p = sc[rg][cf][e];
          unsigned short phi = f2bf(p);
          unsigned short plo = f2bf(p - bf2f(phi));
          int prow = wid * 32 + rg * 16 + kg * 4 + e;
          Ps[prow * 72 + cf * 16 + fl] = phi;
          Ps[prow * 72 + 32 + cf * 16 + fl] = plo;
        }
    }

    // ---- O += P @ V: 3 chunks (Phi*Vhi, Plo*Vhi, Phi*Vlo) ----
    const int PO[3] = {0, 32, 0};
    const int VO[3] = {0, 0, 4};
#pragma unroll
    for (int c = 0; c < 3; ++c) {
      bf16x8 ap0 = *(const bf16x8*)&Ps[(wid * 32 + fl) * 72 + PO[c] + kg * 8];
      bf16x8 ap1 = *(const bf16x8*)&Ps[(wid * 32 + 16 + fl) * 72 + PO[c] + kg * 8];
#pragma unroll
      for (int cf = 0; cf < 4; ++cf) {
        ov[0][cf] = __builtin_amdgcn_mfma_f32_16x16x32_bf16(ap0, vf[VO[c] + cf], ov[0][cf], 0, 0, 0);
        ov[1][cf] = __builtin_amdgcn_mfma_f32_16x16x32_bf16(ap1, vf[VO[c] + cf], ov[1][cf], 0, 0, 0);
      }
    }
  };

  // ---- software-pipelined main loop (x2 unroll, named A/B buffers) ----
  bf16x8 ka[8], kb[8], va[8], vc[8];
  ldk(ka, 0);
  for (int k0 = 0; k0 < SEQ; k0 += 64) {
    ldv(va, k0);           // V(t) in flight under QK+softmax(t)
    ldk(kb, k0 + 32);      // K(t+1) in flight under all of tile t
    tile(ka, va, k0);
    ldv(vc, k0 + 32);
    ldk(ka, k0 + 64);      // last iter: harmless overrun into v2t, unused
    tile(kb, vc, k0 + 32);
  }

  // ---- epilogue: O/l -> split-bf16 into act2 ----
#pragma unroll
  for (int rg = 0; rg < 2; ++rg)
#pragma unroll
    for (int e = 0; e < 4; ++e) {
      float inv = 1.0f / l[rg][e];
      size_t trow = (bS + q0w + rg * 16 + kg * 4 + e) * 1024 + hc;
#pragma unroll
      for (int cf = 0; cf < 4; ++cf) {
        float v = ov[rg][cf][e] * inv;
        unsigned short hi = f2bf(v);
        unsigned short lo = f2bf(v - bf2f(hi));
        o2[trow + cf * 16 + fl] = hi;
        o2[trow + 512 + cf * 16 + fl] = lo;
      }
    }
}

// ---------------------------------------------------------------------------
// Fused residual + LayerNorm: out = LN(X + R) * g + b; optionally emits
// split-bf16 copy (out2, row stride 2*EDIM).
// ---------------------------------------------------------------------------
__global__ __launch_bounds__(128) void ln_res_kernel(
    const float* __restrict__ X, const float* __restrict__ R,
    const float* __restrict__ g, const float* __restrict__ be,
    float* __restrict__ out, unsigned short* __restrict__ out2)
{
  const int row = blockIdx.x;
  const int tid = threadIdx.x;
  const long long off = (long long)row * EDIM + tid * 4;
  float4 xv = *(const float4*)&X[off];
  float4 rv = *(const float4*)&R[off];
  float x0 = xv.x + rv.x, x1 = xv.y + rv.y, x2 = xv.z + rv.z, x3 = xv.w + rv.w;

  __shared__ float red[2];
  float s = (x0 + x1) + (x2 + x3);
#pragma unroll
  for (int o2 = 1; o2 < 64; o2 <<= 1) s += __shfl_xor(s, o2);
  if ((tid & 63) == 0) red[tid >> 6] = s;
  __syncthreads();
  float mean = (red[0] + red[1]) * (1.0f / EDIM);

  float d0 = x0 - mean, d1 = x1 - mean, d2 = x2 - mean, d3 = x3 - mean;
  float s2 = (d0 * d0 + d1 * d1) + (d2 * d2 + d3 * d3);
#pragma unroll
  for (int o2 = 1; o2 < 64; o2 <<= 1) s2 += __shfl_xor(s2, o2);
  __syncthreads();
  if ((tid & 63) == 0) red[tid >> 6] = s2;
  __syncthreads();
  float var = (red[0] + red[1]) * (1.0f / EDIM);
  float rstd = rsqrtf(var + 1e-5f);

  float4 gv = *(const float4*)&g[tid * 4];
  float4 bv = *(const float4*)&be[tid * 4];
  float4 ov;
  ov.x = d0 * rstd * gv.x + bv.x;
  ov.y = d1 * rstd * gv.y + bv.y;
  ov.z = d2 * rstd * gv.z + bv.z;
  ov.w = d3 * rstd * gv.w + bv.w;
  *(float4*)&out[off] = ov;

  if (out2) {
    ushort4 hi, lo;
    splitf(ov.x, &hi.x, &lo.x); splitf(ov.y, &hi.y, &lo.y);
    splitf(ov.z, &hi.z, &lo.z); splitf(ov.w, &hi.w, &lo.w);
    size_t b2 = ((size_t)row << 10) + (size_t)tid * 4;
    *(ushort4*)&out2[b2] = hi;
    *(ushort4*)&out2[b2 + EDIM] = lo;
  }
}

// ---------------------------------------------------------------------------
extern "C" void kernel_launch(void* const* d_in, const int* in_sizes, int n_in,
                              void* d_out, int out_size, void* d_ws, size_t ws_size,
                              hipStream_t stream) {
  (void)in_sizes; (void)n_in; (void)out_size; (void)ws_size;

  const int*   x    = (const int*)d_in[0];
  const int*   mask = (const int*)d_in[1];
  const float* emb  = (const float*)d_in[2];
  const float* pos  = (const float*)d_in[3];
  const float* Wq   = (const float*)d_in[4];
  const float* Wk   = (const float*)d_in[5];
  const float* Wv   = (const float*)d_in[6];
  const float* Wo   = (const float*)d_in[7];
  const float* bo   = (const float*)d_in[8];
  const float* ln1g = (const float*)d_in[9];
  const float* ln1b = (const float*)d_in[10];
  const float* ln2g = (const float*)d_in[11];
  const float* ln2b = (const float*)d_in[12];
  const float* Wf1  = (const float*)d_in[13];
  const float* bf1  = (const float*)d_in[14];
  const float* Wf2  = (const float*)d_in[15];
  const float* bf2  = (const float*)d_in[16];
  float* out = (float*)d_out;

  // ws layout:
  //   hb (MEL f32) | h1 (MEL f32) | region (4*MEL f32 = 67MB):
  //     during attn: q2 [2MEL,3MEL) + k2 [3,4) + v2t [4,5)  [split bf16]
  //     after attn:  t1 (fp32 M x E) aliases q2; later ff2 (bf16 M x 4096)
  //   act2 (M x 1024 bf16) | weight splits
  float* hb = (float*)d_ws;
  float* h1 = hb + MEL;
  unsigned short* q2  = (unsigned short*)(hb + 2 * MEL);
  unsigned short* k2  = q2 + (size_t)MTOK * 1024;
  unsigned short* v2t = k2 + (size_t)MTOK * 1024;   // [512 n][hi 8192 | lo 8192]
  float* t1 = (float*)(hb + 2 * MEL);               // alias q2 (dead post-attn)
  unsigned short* ff2 = (unsigned short*)(hb + 2 * MEL);  // alias whole region
  unsigned short* act2 = (unsigned short*)(hb + 6 * MEL); // M x 1024
  unsigned short* wq2  = act2 + (size_t)MTOK * 1024;      // 512 x 1024 each
  unsigned short* wk2  = wq2 + 512 * 1024;
  unsigned short* wv2  = wk2 + 512 * 1024;
  unsigned short* wo2  = wv2 + 512 * 1024;
  unsigned short* wf12 = wo2 + 512 * 1024;                // 2048 x 1024
  unsigned short* wf22 = wf12 + (size_t)2048 * 1024;      // 512 x 4096

  embed_kernel<<<dim3(MTOK * (EDIM / 4) / 256), 256, 0, stream>>>(x, emb, pos, hb, act2);

  for (int l = 0; l < NLAYER; ++l) {
    const float* wq = Wq + (long long)l * EDIM * EDIM;
    const float* wk = Wk + (long long)l * EDIM * EDIM;
    const float* wv = Wv + (long long)l * EDIM * EDIM;
    const float* wo = Wo + (long long)l * EDIM * EDIM;
    const float* wf1 = Wf1 + (long long)l * FFD * EDIM;
    const float* wf2 = Wf2 + (long long)l * EDIM * FFD;

    // weight hi/lo splits
    split_kernel<<<dim3(256), 256, 0, stream>>>(wq, wq2, 7);      // 512 x 512
    split_kernel<<<dim3(256), 256, 0, stream>>>(wk, wk2, 7);
    split_kernel<<<dim3(256), 256, 0, stream>>>(wv, wv2, 7);
    split_kernel<<<dim3(256), 256, 0, stream>>>(wo, wo2, 7);
    split_kernel<<<dim3(1024), 256, 0, stream>>>(wf1, wf12, 7);   // 2048 x 512
    split_kernel<<<dim3(1024), 256, 0, stream>>>(wf2, wf22, 9);   // 512 x 2048

    // Q,K projections (fused via grid.z), split-bf16 out token-major
    gemm_split<<<dim3(EDIM / 128, MTOK / 128, 2), 256, 0, stream>>>(
        act2, wq2, wk2, nullptr, q2, (long long)MTOK * 1024, nullptr,
        EDIM, EDIM, 1, 0);

    // V projection with SWAPPED operands -> V^T directly: C[n][token]
    gemm_split<<<dim3(MTOK / 128, EDIM / 128, 1), 256, 0, stream>>>(
        wv2, act2, nullptr, nullptr, v2t, 0, nullptr,
        MTOK, EDIM, 1, 0);

    // flash attention v3 (MFMA, global-direct K/V + reg prefetch)
    attn_mfma<<<dim3(SEQ / 128, BATCH * NH), 256, 0, stream>>>(
        q2, k2, v2t, mask, act2);

    // output projection (+bo), fp32 out
    gemm_split<<<dim3(EDIM / 128, MTOK / 128, 1), 256, 0, stream>>>(
        act2, wo2, nullptr, nullptr, t1, 0, bo + (long long)l * EDIM,
        EDIM, EDIM, 0, 0);

    // h1 = LN(t1 + h), emit split-bf16 h1 for FFN
    ln_res_kernel<<<MTOK, 128, 0, stream>>>(
        t1, hb, ln1g + (long long)l * EDIM, ln1b + (long long)l * EDIM, h1, act2);

    // ff = relu(h1 @ Wf1^T + bf1), split-bf16 out
    gemm_split<<<dim3(FFD / 128, MTOK / 128, 1), 256, 0, stream>>>(
        act2, wf12, nullptr, nullptr, ff2, 0, bf1 + (long long)l * FFD,
        FFD, EDIM, 1, 1);

    // ff @ Wf2^T + bf2, fp32 out -> hb (old h dead after LN1)
    gemm_split<<<dim3(EDIM / 128, MTOK / 128, 1), 256, 0, stream>>>(
        ff2, wf22, nullptr, nullptr, hb, 0, bf2 + (long long)l * EDIM,
        EDIM, FFD, 0, 0);

    // h = LN(hb + h1); final layer -> d_out
    float* lnout = (l == NLAYER - 1) ? out : hb;
    unsigned short* lnout2 = (l == NLAYER - 1) ? nullptr : act2;
    ln_res_kernel<<<MTOK, 128, 0, stream>>>(
        hb, h1, ln2g + (long long)l * EDIM, ln2b + (long long)l * EDIM, lnout, lnout2);
  }
}

// Round 8
// 1045.740 us; speedup vs baseline: 1.5848x; 1.3967x over previous
//
#include <hip/hip_runtime.h>
#include <math.h>

// Problem constants (fixed by the reference)
#define BATCH 4
#define SEQ   2048
#define EDIM  512
#define NH    8
#define HD    64
#define FFD   2048
#define NLAYER 2
#define MTOK  (BATCH * SEQ)            // 8192 rows
#define MEL   ((long long)MTOK * EDIM) // 4194304 elements per (M,E) buffer

typedef __attribute__((ext_vector_type(8))) short bf16x8;
typedef __attribute__((ext_vector_type(4))) float f32x4;

// ---------------------------------------------------------------------------
// fp32 <-> split-bf16 helpers: a ≈ hi + lo, each bf16 (RNE), ~16 mantissa bits
// ---------------------------------------------------------------------------
__device__ __forceinline__ unsigned short f2bf(float f) {
  unsigned u = __float_as_uint(f);
  u += 0x7fffu + ((u >> 16) & 1u);     // round to nearest even
  return (unsigned short)(u >> 16);
}
__device__ __forceinline__ float bf2f(unsigned short h) {
  return __uint_as_float(((unsigned)h) << 16);
}
__device__ __forceinline__ void splitf(float v, unsigned short* hi, unsigned short* lo) {
  unsigned short h = f2bf(v);
  *hi = h;
  *lo = f2bf(v - bf2f(h));
}

// ---------------------------------------------------------------------------
// Embedding + positional encoding; emits fp32 h (residual) + split-bf16 h2.
// ---------------------------------------------------------------------------
__global__ __launch_bounds__(256) void embed_kernel(
    const int* __restrict__ x, const float* __restrict__ emb,
    const float* __restrict__ pos, float* __restrict__ h,
    unsigned short* __restrict__ h2)
{
  int idx = blockIdx.x * 256 + threadIdx.x;   // over MTOK * (EDIM/4)
  int t = idx >> 7;                           // EDIM/4 = 128 float4 per row
  int c = idx & 127;
  int s = t & (SEQ - 1);
  int v = x[t];
  float4 ev = ((const float4*)emb)[(long long)v * 128 + c];
  float4 pv = ((const float4*)pos)[(long long)s * 128 + c];
  float4 r;
  r.x = ev.x + pv.x; r.y = ev.y + pv.y; r.z = ev.z + pv.z; r.w = ev.w + pv.w;
  ((float4*)h)[idx] = r;

  ushort4 hi, lo;
  splitf(r.x, &hi.x, &lo.x); splitf(r.y, &hi.y, &lo.y);
  splitf(r.z, &hi.z, &lo.z); splitf(r.w, &hi.w, &lo.w);
  size_t base = ((size_t)t << 10) + (size_t)c * 4;   // row stride 2*EDIM=1024
  *(ushort4*)&h2[base] = hi;
  *(ushort4*)&h2[base + EDIM] = lo;
}

// ---------------------------------------------------------------------------
// Generic fp32 (rows x K) -> split-bf16 (rows x 2K, [hi | lo]) converter.
// K = 4<<shift. Used for weights only.
// ---------------------------------------------------------------------------
__global__ __launch_bounds__(256) void split_kernel(
    const float* __restrict__ src, unsigned short* __restrict__ dst, int shift)
{
  int idx = blockIdx.x * 256 + threadIdx.x;
  int row = idx >> shift;
  int c4 = idx & ((1 << shift) - 1);
  int Koff = 4 << shift;
  float4 v = ((const float4*)src)[idx];
  ushort4 hi, lo;
  splitf(v.x, &hi.x, &lo.x); splitf(v.y, &hi.y, &lo.y);
  splitf(v.z, &hi.z, &lo.z); splitf(v.w, &hi.w, &lo.w);
  size_t base = ((size_t)row << (shift + 3)) + (size_t)c4 * 4;  // row stride 2K
  *(ushort4*)&dst[base] = hi;
  *(ushort4*)&dst[base + Koff] = lo;
}

// ---------------------------------------------------------------------------
// Split-bf16 GEMM: C[M x N] = A[M x K] * W[N x K]^T (+bias)(+relu); A,W stored
// as [hi | lo] bf16 rows (stride 2K).
// chunks=3: virtual K'=3K (A_hi*B_hi + A_lo*B_hi + A_hi*B_lo), ~1e-5 rel.
// chunks=1: hi*hi only (plain bf16 GEMM over the hi halves), ~4e-3 rel —
//           used for Q/K/V projections (feed bf16 attention; precision audit
//           in attn_mfma header).
// m97 structure: 128x128 tile, BK=64, 4 waves, mfma_f32_16x16x32_bf16,
// linear LDS, global_load_lds width 16.
// outmode 0: fp32 C;  outmode 1: split-bf16 C (rows [hi N | lo N], stride 2N);
// outmode 2: plain bf16 C (row stride N).
// All modes offset C by blockIdx.z * czstride (elements); B selected by z.
// ---------------------------------------------------------------------------
__global__ __launch_bounds__(256) void gemm_split(
    const unsigned short* __restrict__ A,
    const unsigned short* __restrict__ B0,
    const unsigned short* __restrict__ B1,
    const unsigned short* __restrict__ B2,
    void* __restrict__ Cbase, long long czstride,
    const float* __restrict__ bias,
    int N, int K, int outmode, int relu, int chunks)
{
  __shared__ unsigned short As[128 * 64];
  __shared__ unsigned short Bs[128 * 64];

  const int tid = threadIdx.x;
  const int lane = tid & 63;
  const int wid = tid >> 6;           // wave 0..3
  const int wr = wid >> 1, wc = wid & 1;
  const int fl = lane & 15;           // fragment row/col
  const int kg = lane >> 4;           // k-group 0..3
  const int z = blockIdx.z;
  const unsigned short* __restrict__ B = (z == 0) ? B0 : ((z == 1) ? B1 : B2);
  const int brow = blockIdx.y * 128;
  const int bcol = blockIdx.x * 128;
  const int ld = 2 * K;

  f32x4 acc[4][4];
#pragma unroll
  for (int i = 0; i < 4; ++i)
#pragma unroll
    for (int j = 0; j < 4; ++j) acc[i][j] = (f32x4){0.f, 0.f, 0.f, 0.f};

  const int r0 = lane >> 3;
  const int c0 = (lane & 7) * 8;

  for (int kt = 0; kt < chunks * K; kt += 64) {
    const int akt = (kt < 2 * K) ? kt : kt - 2 * K;  // hi, lo, hi
    const int bkt = (kt < K) ? kt : kt - K;          // hi, hi, lo
#pragma unroll
    for (int i = 0; i < 4; ++i) {
      const int chunk = i * 4 + wid;                 // 16 chunks of 8 rows
      const int r = chunk * 8 + r0;
      const unsigned short* ga = A + (size_t)(brow + r) * ld + akt + c0;
      const unsigned short* gb = B + (size_t)(bcol + r) * ld + bkt + c0;
      __builtin_amdgcn_global_load_lds(
          (const __attribute__((address_space(1))) void*)ga,
          (__attribute__((address_space(3))) void*)&As[chunk * 512 + lane * 8],
          16, 0, 0);
      __builtin_amdgcn_global_load_lds(
          (const __attribute__((address_space(1))) void*)gb,
          (__attribute__((address_space(3))) void*)&Bs[chunk * 512 + lane * 8],
          16, 0, 0);
    }
    __syncthreads();   // drains vmcnt -> LDS tile ready
#pragma unroll
    for (int kk = 0; kk < 2; ++kk) {
      bf16x8 av[4], bv[4];
#pragma unroll
      for (int f = 0; f < 4; ++f) {
        av[f] = *(const bf16x8*)&As[(wr * 64 + f * 16 + fl) * 64 + kk * 32 + kg * 8];
        bv[f] = *(const bf16x8*)&Bs[(wc * 64 + f * 16 + fl) * 64 + kk * 32 + kg * 8];
      }
#pragma unroll
      for (int i = 0; i < 4; ++i)
#pragma unroll
        for (int j = 0; j < 4; ++j)
          acc[i][j] = __builtin_amdgcn_mfma_f32_16x16x32_bf16(av[i], bv[j], acc[i][j], 0, 0, 0);
    }
    __syncthreads();   // tile consumed before next stage overwrites
  }

  // epilogue — C/D layout: col = lane&15, row = (lane>>4)*4 + reg  [m89]
  if (outmode == 0) {
    float* C = (float*)Cbase + (size_t)z * czstride;
#pragma unroll
    for (int j = 0; j < 4; ++j) {
      const int col = bcol + wc * 64 + j * 16 + fl;
      const float bb = bias ? bias[col] : 0.f;
#pragma unroll
      for (int i = 0; i < 4; ++i) {
        const int rowb = brow + wr * 64 + i * 16 + kg * 4;
#pragma unroll
        for (int e = 0; e < 4; ++e) {
          float v = acc[i][j][e] + bb;
          if (relu) v = fmaxf(v, 0.f);
          C[(size_t)(rowb + e) * N + col] = v;
        }
      }
    }
  } else if (outmode == 1) {
    unsigned short* C = (unsigned short*)Cbase + (size_t)z * czstride;
#pragma unroll
    for (int j = 0; j < 4; ++j) {
      const int col = bcol + wc * 64 + j * 16 + fl;
      const float bb = bias ? bias[col] : 0.f;
#pragma unroll
      for (int i = 0; i < 4; ++i) {
        const int rowb = brow + wr * 64 + i * 16 + kg * 4;
#pragma unroll
        for (int e = 0; e < 4; ++e) {
          float v = acc[i][j][e] + bb;
          if (relu) v = fmaxf(v, 0.f);
          unsigned short hi, lo;
          splitf(v, &hi, &lo);
          size_t rb = (size_t)(rowb + e) * (2 * (size_t)N);
          C[rb + col] = hi;
          C[rb + N + col] = lo;
        }
      }
    }
  } else {
    unsigned short* C = (unsigned short*)Cbase + (size_t)z * czstride;
#pragma unroll
    for (int j = 0; j < 4; ++j) {
      const int col = bcol + wc * 64 + j * 16 + fl;
      const float bb = bias ? bias[col] : 0.f;
#pragma unroll
      for (int i = 0; i < 4; ++i) {
        const int rowb = brow + wr * 64 + i * 16 + kg * 4;
#pragma unroll
        for (int e = 0; e < 4; ++e) {
          float v = acc[i][j][e] + bb;
          if (relu) v = fmaxf(v, 0.f);
          C[(size_t)(rowb + e) * N + col] = f2bf(v);
        }
      }
    }
  }
}

// ---------------------------------------------------------------------------
// MFMA flash attention v4: PLAIN BF16 (hi-only) QK^T and PV.
// Round-6 PMC: 314us, MfmaUtil 13.6, VALUBusy 29 -> chain-latency bound; the
// split machinery (3x MFMA chunks, 2x loads, f2bf lo-splits) dominated the
// serial chain. Precision audit: |energy|<~8, x1/sqrt(2048) -> bf16 q/k gives
// P rel err ~1e-3; O err ~4e-5 abs; O feeds a 0.003-scale Wo output vs O(1)
// residual -> final absmax contribution ~1e-4 (margin: passing at 0.0156).
// Inputs: q2/k2 plain bf16 token-major (stride 512); v2t plain bf16 V^T
// [n=h*64+d][8192 tok]. K frags double-buffered (T14), V issued at tile top.
// Output: split-bf16 into act2 (preserves Wo input precision). No barriers.
// ---------------------------------------------------------------------------
__global__ __launch_bounds__(256, 2) void attn_mfma(
    const unsigned short* __restrict__ q2,
    const unsigned short* __restrict__ k2,
    const unsigned short* __restrict__ v2t,
    const int* __restrict__ maskg,
    unsigned short* __restrict__ o2)
{
  __shared__ unsigned short Ps[128 * 40];   // [q-row][32 bf16 P | pad]

  const int tid = threadIdx.x;
  const int lane = tid & 63;
  const int wid = tid >> 6;
  const int fl = lane & 15;
  const int kg = lane >> 4;
  const int b = blockIdx.y >> 3, h = blockIdx.y & 7;
  const int hc = h * 64;
  const int q0w = blockIdx.x * 128 + wid * 32;   // this wave's q block
  const float inv_scale = 0.022097086912079608f; // 1/sqrt(2048)
  const size_t bS = (size_t)b * SEQ;

  // hoisted Q fragments (rows q0w+rg*16+fl): {d0-32, d32-64}
  bf16x8 aq[2][2];
#pragma unroll
  for (int rg = 0; rg < 2; ++rg) {
    size_t qr = (bS + q0w + rg * 16 + fl) * 512 + hc + kg * 8;
    aq[rg][0] = *(const bf16x8*)&q2[qr];
    aq[rg][1] = *(const bf16x8*)&q2[qr + 32];
  }

  // per-lane K/V fragment base pointers
  const unsigned short* kp0 = k2 + (bS + fl) * 512 + hc + kg * 8;       // cf=0
  const unsigned short* kp1 = k2 + (bS + 16 + fl) * 512 + hc + kg * 8;  // cf=1
  const unsigned short* vbp[4];
#pragma unroll
  for (int cf = 0; cf < 4; ++cf)
    vbp[cf] = v2t + (size_t)(hc + cf * 16 + fl) * 8192 + bS + kg * 8;
  const int* mrow = maskg + bS;

  float m[2][4], l[2][4];
  f32x4 ov[2][4];
#pragma unroll
  for (int rg = 0; rg < 2; ++rg) {
#pragma unroll
    for (int e = 0; e < 4; ++e) { m[rg][e] = -INFINITY; l[rg][e] = 0.f; }
#pragma unroll
    for (int cf = 0; cf < 4; ++cf) ov[rg][cf] = (f32x4){0.f, 0.f, 0.f, 0.f};
  }

  // unique K frags per tile: {d0-32, d32-64} x {row grp 0,1}
  auto ldk = [&](bf16x8 (&kf)[4], int k0) {
    size_t kr = (size_t)k0 * 512;
    kf[0] = *(const bf16x8*)(kp0 + kr);
    kf[1] = *(const bf16x8*)(kp0 + kr + 32);
    kf[2] = *(const bf16x8*)(kp1 + kr);
    kf[3] = *(const bf16x8*)(kp1 + kr + 32);
  };
  // unique V frags per tile: 4 cf
  auto ldv = [&](bf16x8 (&vf)[4], int k0) {
#pragma unroll
    for (int cf = 0; cf < 4; ++cf)
      vf[cf] = *(const bf16x8*)(vbp[cf] + k0);
  };

  auto tile = [&](const bf16x8 (&kf)[4], const bf16x8 (&vf)[4], int k0) {
    const bool dead0 = (mrow[k0 + fl] == 0);
    const bool dead1 = (mrow[k0 + 16 + fl] == 0);

    // ---- QK^T: 2 d-chunks x 2 col-frags x 2 row-grps = 8 MFMA ----
    f32x4 sc[2][2];
#pragma unroll
    for (int rg = 0; rg < 2; ++rg)
#pragma unroll
      for (int cf = 0; cf < 2; ++cf) sc[rg][cf] = (f32x4){0.f, 0.f, 0.f, 0.f};

#pragma unroll
    for (int c = 0; c < 2; ++c) {
      sc[0][0] = __builtin_amdgcn_mfma_f32_16x16x32_bf16(aq[0][c], kf[c], sc[0][0], 0, 0, 0);
      sc[1][0] = __builtin_amdgcn_mfma_f32_16x16x32_bf16(aq[1][c], kf[c], sc[1][0], 0, 0, 0);
      sc[0][1] = __builtin_amdgcn_mfma_f32_16x16x32_bf16(aq[0][c], kf[2 + c], sc[0][1], 0, 0, 0);
      sc[1][1] = __builtin_amdgcn_mfma_f32_16x16x32_bf16(aq[1][c], kf[2 + c], sc[1][1], 0, 0, 0);
    }

    // ---- mask + scale + online softmax (lane rows = kg*4+e) ----
#pragma unroll
    for (int rg = 0; rg < 2; ++rg) {
#pragma unroll
      for (int e = 0; e < 4; ++e) {
        float s0 = dead0 ? -1e20f : sc[rg][0][e];
        float s1 = dead1 ? -1e20f : sc[rg][1][e];
        sc[rg][0][e] = s0 * inv_scale;
        sc[rg][1][e] = s1 * inv_scale;
      }
#pragma unroll
      for (int e = 0; e < 4; ++e) {
        float rm = fmaxf(sc[rg][0][e], sc[rg][1][e]);
        rm = fmaxf(rm, __shfl_xor(rm, 1));
        rm = fmaxf(rm, __shfl_xor(rm, 2));
        rm = fmaxf(rm, __shfl_xor(rm, 4));
        rm = fmaxf(rm, __shfl_xor(rm, 8));
        float mnew = fmaxf(m[rg][e], rm);
        float corr = __expf(m[rg][e] - mnew);   // first tile: exp(-inf)=0
        float p0 = __expf(sc[rg][0][e] - mnew);
        float p1 = __expf(sc[rg][1][e] - mnew);
        sc[rg][0][e] = p0; sc[rg][1][e] = p1;
        float ps = p0 + p1;
        ps += __shfl_xor(ps, 1); ps += __shfl_xor(ps, 2);
        ps += __shfl_xor(ps, 4); ps += __shfl_xor(ps, 8);
        l[rg][e] = l[rg][e] * corr + ps;
        m[rg][e] = mnew;
#pragma unroll
        for (int cf = 0; cf < 4; ++cf) ov[rg][cf][e] *= corr;
      }
      // P -> LDS, plain bf16 (wave-exclusive rows; same-wave RAW, no barrier)
#pragma unroll
      for (int cf = 0; cf < 2; ++cf)
#pragma unroll
        for (int e = 0; e < 4; ++e) {
          int prow = wid * 32 + rg * 16 + kg * 4 + e;
          Ps[prow * 40 + cf * 16 + fl] = f2bf(sc[rg][cf][e]);
        }
    }

    // ---- O += P @ V: 1 chunk, 8 MFMA ----
    bf16x8 ap0 = *(const bf16x8*)&Ps[(wid * 32 + fl) * 40 + kg * 8];
    bf16x8 ap1 = *(const bf16x8*)&Ps[(wid * 32 + 16 + fl) * 40 + kg * 8];
#pragma unroll
    for (int cf = 0; cf < 4; ++cf) {
      ov[0][cf] = __builtin_amdgcn_mfma_f32_16x16x32_bf16(ap0, vf[cf], ov[0][cf], 0, 0, 0);
      ov[1][cf] = __builtin_amdgcn_mfma_f32_16x16x32_bf16(ap1, vf[cf], ov[1][cf], 0, 0, 0);
    }
  };

  // ---- software-pipelined main loop (x2 unroll, named A/B buffers) ----
  bf16x8 ka[4], kb[4], va[4], vc[4];
  ldk(ka, 0);
  for (int k0 = 0; k0 < SEQ; k0 += 64) {
    ldv(va, k0);           // V(t) in flight under QK+softmax(t)
    ldk(kb, k0 + 32);      // K(t+1) in flight under all of tile t
    tile(ka, va, k0);
    ldv(vc, k0 + 32);
    ldk(ka, k0 + 64);      // last iter: harmless overrun into v2t, unused
    tile(kb, vc, k0 + 32);
  }

  // ---- epilogue: O/l -> split-bf16 into act2 (Wo input precision kept) ----
#pragma unroll
  for (int rg = 0; rg < 2; ++rg)
#pragma unroll
    for (int e = 0; e < 4; ++e) {
      float inv = 1.0f / l[rg][e];
      size_t trow = (bS + q0w + rg * 16 + kg * 4 + e) * 1024 + hc;
#pragma unroll
      for (int cf = 0; cf < 4; ++cf) {
        float v = ov[rg][cf][e] * inv;
        unsigned short hi = f2bf(v);
        unsigned short lo = f2bf(v - bf2f(hi));
        o2[trow + cf * 16 + fl] = hi;
        o2[trow + 512 + cf * 16 + fl] = lo;
      }
    }
}

// ---------------------------------------------------------------------------
// Fused residual + LayerNorm: out = LN(X + R) * g + b; optionally emits
// split-bf16 copy (out2, row stride 2*EDIM).
// ---------------------------------------------------------------------------
__global__ __launch_bounds__(128) void ln_res_kernel(
    const float* __restrict__ X, const float* __restrict__ R,
    const float* __restrict__ g, const float* __restrict__ be,
    float* __restrict__ out, unsigned short* __restrict__ out2)
{
  const int row = blockIdx.x;
  const int tid = threadIdx.x;
  const long long off = (long long)row * EDIM + tid * 4;
  float4 xv = *(const float4*)&X[off];
  float4 rv = *(const float4*)&R[off];
  float x0 = xv.x + rv.x, x1 = xv.y + rv.y, x2 = xv.z + rv.z, x3 = xv.w + rv.w;

  __shared__ float red[2];
  float s = (x0 + x1) + (x2 + x3);
#pragma unroll
  for (int o2 = 1; o2 < 64; o2 <<= 1) s += __shfl_xor(s, o2);
  if ((tid & 63) == 0) red[tid >> 6] = s;
  __syncthreads();
  float mean = (red[0] + red[1]) * (1.0f / EDIM);

  float d0 = x0 - mean, d1 = x1 - mean, d2 = x2 - mean, d3 = x3 - mean;
  float s2 = (d0 * d0 + d1 * d1) + (d2 * d2 + d3 * d3);
#pragma unroll
  for (int o2 = 1; o2 < 64; o2 <<= 1) s2 += __shfl_xor(s2, o2);
  __syncthreads();
  if ((tid & 63) == 0) red[tid >> 6] = s2;
  __syncthreads();
  float var = (red[0] + red[1]) * (1.0f / EDIM);
  float rstd = rsqrtf(var + 1e-5f);

  float4 gv = *(const float4*)&g[tid * 4];
  float4 bv = *(const float4*)&be[tid * 4];
  float4 ov;
  ov.x = d0 * rstd * gv.x + bv.x;
  ov.y = d1 * rstd * gv.y + bv.y;
  ov.z = d2 * rstd * gv.z + bv.z;
  ov.w = d3 * rstd * gv.w + bv.w;
  *(float4*)&out[off] = ov;

  if (out2) {
    ushort4 hi, lo;
    splitf(ov.x, &hi.x, &lo.x); splitf(ov.y, &hi.y, &lo.y);
    splitf(ov.z, &hi.z, &lo.z); splitf(ov.w, &hi.w, &lo.w);
    size_t b2 = ((size_t)row << 10) + (size_t)tid * 4;
    *(ushort4*)&out2[b2] = hi;
    *(ushort4*)&out2[b2 + EDIM] = lo;
  }
}

// ---------------------------------------------------------------------------
extern "C" void kernel_launch(void* const* d_in, const int* in_sizes, int n_in,
                              void* d_out, int out_size, void* d_ws, size_t ws_size,
                              hipStream_t stream) {
  (void)in_sizes; (void)n_in; (void)out_size; (void)ws_size;

  const int*   x    = (const int*)d_in[0];
  const int*   mask = (const int*)d_in[1];
  const float* emb  = (const float*)d_in[2];
  const float* pos  = (const float*)d_in[3];
  const float* Wq   = (const float*)d_in[4];
  const float* Wk   = (const float*)d_in[5];
  const float* Wv   = (const float*)d_in[6];
  const float* Wo   = (const float*)d_in[7];
  const float* bo   = (const float*)d_in[8];
  const float* ln1g = (const float*)d_in[9];
  const float* ln1b = (const float*)d_in[10];
  const float* ln2g = (const float*)d_in[11];
  const float* ln2b = (const float*)d_in[12];
  const float* Wf1  = (const float*)d_in[13];
  const float* bf1  = (const float*)d_in[14];
  const float* Wf2  = (const float*)d_in[15];
  const float* bf2  = (const float*)d_in[16];
  float* out = (float*)d_out;

  // ws layout:
  //   hb (MEL f32) | h1 (MEL f32) | region (4*MEL f32 = 67MB):
  //     during attn: q2/k2 (M x 512 bf16 each) + v2t ([512][8192] bf16)
  //     after attn:  t1 (fp32 M x E) aliases q2; later ff2 (bf16 M x 4096)
  //   act2 (M x 1024 bf16) | weight splits
  float* hb = (float*)d_ws;
  float* h1 = hb + MEL;
  unsigned short* q2  = (unsigned short*)(hb + 2 * MEL);
  unsigned short* k2  = q2 + (size_t)MTOK * 512;
  unsigned short* v2t = k2 + (size_t)MTOK * 512;    // [512 n][8192 tok]
  float* t1 = (float*)(hb + 2 * MEL);               // alias q2 (dead post-attn)
  unsigned short* ff2 = (unsigned short*)(hb + 2 * MEL);  // alias whole region
  unsigned short* act2 = (unsigned short*)(hb + 6 * MEL); // M x 1024
  unsigned short* wq2  = act2 + (size_t)MTOK * 1024;      // 512 x 1024 each
  unsigned short* wk2  = wq2 + 512 * 1024;
  unsigned short* wv2  = wk2 + 512 * 1024;
  unsigned short* wo2  = wv2 + 512 * 1024;
  unsigned short* wf12 = wo2 + 512 * 1024;                // 2048 x 1024
  unsigned short* wf22 = wf12 + (size_t)2048 * 1024;      // 512 x 4096

  embed_kernel<<<dim3(MTOK * (EDIM / 4) / 256), 256, 0, stream>>>(x, emb, pos, hb, act2);

  for (int l = 0; l < NLAYER; ++l) {
    const float* wq = Wq + (long long)l * EDIM * EDIM;
    const float* wk = Wk + (long long)l * EDIM * EDIM;
    const float* wv = Wv + (long long)l * EDIM * EDIM;
    const float* wo = Wo + (long long)l * EDIM * EDIM;
    const float* wf1 = Wf1 + (long long)l * FFD * EDIM;
    const float* wf2 = Wf2 + (long long)l * EDIM * FFD;

    // weight hi/lo splits
    split_kernel<<<dim3(256), 256, 0, stream>>>(wq, wq2, 7);      // 512 x 512
    split_kernel<<<dim3(256), 256, 0, stream>>>(wk, wk2, 7);
    split_kernel<<<dim3(256), 256, 0, stream>>>(wv, wv2, 7);
    split_kernel<<<dim3(256), 256, 0, stream>>>(wo, wo2, 7);
    split_kernel<<<dim3(1024), 256, 0, stream>>>(wf1, wf12, 7);   // 2048 x 512
    split_kernel<<<dim3(1024), 256, 0, stream>>>(wf2, wf22, 9);   // 512 x 2048

    // Q,K projections: hi-only bf16 GEMM (chunks=1), plain bf16 out
    gemm_split<<<dim3(EDIM / 128, MTOK / 128, 2), 256, 0, stream>>>(
        act2, wq2, wk2, nullptr, q2, (long long)MTOK * 512, nullptr,
        EDIM, EDIM, 2, 0, 1);

    // V projection, SWAPPED operands -> V^T [n][token], bf16 out, hi-only
    gemm_split<<<dim3(MTOK / 128, EDIM / 128, 1), 256, 0, stream>>>(
        wv2, act2, nullptr, nullptr, v2t, 0, nullptr,
        MTOK, EDIM, 2, 0, 1);

    // flash attention v4 (plain-bf16 MFMA, global-direct K/V + reg prefetch)
    attn_mfma<<<dim3(SEQ / 128, BATCH * NH), 256, 0, stream>>>(
        q2, k2, v2t, mask, act2);

    // output projection (+bo), full split precision, fp32 out
    gemm_split<<<dim3(EDIM / 128, MTOK / 128, 1), 256, 0, stream>>>(
        act2, wo2, nullptr, nullptr, t1, 0, bo + (long long)l * EDIM,
        EDIM, EDIM, 0, 0, 3);

    // h1 = LN(t1 + h), emit split-bf16 h1 for FFN
    ln_res_kernel<<<MTOK, 128, 0, stream>>>(
        t1, hb, ln1g + (long long)l * EDIM, ln1b + (long long)l * EDIM, h1, act2);

    // ff = relu(h1 @ Wf1^T + bf1), split-bf16 out
    gemm_split<<<dim3(FFD / 128, MTOK / 128, 1), 256, 0, stream>>>(
        act2, wf12, nullptr, nullptr, ff2, 0, bf1 + (long long)l * FFD,
        FFD, EDIM, 1, 1, 3);

    // ff @ Wf2^T + bf2, fp32 out -> hb (old h dead after LN1)
    gemm_split<<<dim3(EDIM / 128, MTOK / 128, 1), 256, 0, stream>>>(
        ff2, wf22, nullptr, nullptr, hb, 0, bf2 + (long long)l * EDIM,
        EDIM, FFD, 0, 0, 3);

    // h = LN(hb + h1); final layer -> d_out
    float* lnout = (l == NLAYER - 1) ? out : hb;
    unsigned short* lnout2 = (l == NLAYER - 1) ? nullptr : act2;
    ln_res_kernel<<<MTOK, 128, 0, stream>>>(
        hb, h1, ln2g + (long long)l * EDIM, ln2b + (long long)l * EDIM, lnout, lnout2);
  }
}

// Round 11
// 987.294 us; speedup vs baseline: 1.6787x; 1.0592x over previous
//
#include <hip/hip_runtime.h>
#include <math.h>

// Problem constants (fixed by the reference)
#define BATCH 4
#define SEQ   2048
#define EDIM  512
#define NH    8
#define HD    64
#define FFD   2048
#define NLAYER 2
#define MTOK  (BATCH * SEQ)            // 8192 rows
#define MEL   ((long long)MTOK * EDIM) // 4194304 elements per (M,E) buffer

typedef __attribute__((ext_vector_type(8))) short bf16x8;
typedef __attribute__((ext_vector_type(4))) float f32x4;
typedef __attribute__((ext_vector_type(8))) _Float16 f16x8;
typedef __attribute__((ext_vector_type(4))) _Float16 f16x4;

// ---------------------------------------------------------------------------
// fp32 <-> split-bf16 helpers: a ≈ hi + lo, each bf16 (RNE), ~16 mantissa bits
// ---------------------------------------------------------------------------
__device__ __forceinline__ unsigned short f2bf(float f) {
  unsigned u = __float_as_uint(f);
  u += 0x7fffu + ((u >> 16) & 1u);     // round to nearest even
  return (unsigned short)(u >> 16);
}
__device__ __forceinline__ float bf2f(unsigned short h) {
  return __uint_as_float(((unsigned)h) << 16);
}
__device__ __forceinline__ void splitf(float v, unsigned short* hi, unsigned short* lo) {
  unsigned short h = f2bf(v);
  *hi = h;
  *lo = f2bf(v - bf2f(h));
}

// ---------------------------------------------------------------------------
// Embedding + positional encoding; emits fp32 h (residual) + split-bf16 h2.
// ---------------------------------------------------------------------------
__global__ __launch_bounds__(256) void embed_kernel(
    const int* __restrict__ x, const float* __restrict__ emb,
    const float* __restrict__ pos, float* __restrict__ h,
    unsigned short* __restrict__ h2)
{
  int idx = blockIdx.x * 256 + threadIdx.x;   // over MTOK * (EDIM/4)
  int t = idx >> 7;                           // EDIM/4 = 128 float4 per row
  int c = idx & 127;
  int s = t & (SEQ - 1);
  int v = x[t];
  float4 ev = ((const float4*)emb)[(long long)v * 128 + c];
  float4 pv = ((const float4*)pos)[(long long)s * 128 + c];
  float4 r;
  r.x = ev.x + pv.x; r.y = ev.y + pv.y; r.z = ev.z + pv.z; r.w = ev.w + pv.w;
  ((float4*)h)[idx] = r;

  ushort4 hi, lo;
  splitf(r.x, &hi.x, &lo.x); splitf(r.y, &hi.y, &lo.y);
  splitf(r.z, &hi.z, &lo.z); splitf(r.w, &hi.w, &lo.w);
  size_t base = ((size_t)t << 10) + (size_t)c * 4;   // row stride 2*EDIM=1024
  *(ushort4*)&h2[base] = hi;
  *(ushort4*)&h2[base + EDIM] = lo;
}

// ---------------------------------------------------------------------------
// Generic fp32 (rows x K) -> split-bf16 (rows x 2K, [hi | lo]) converter.
// K = 4<<shift. Used for weights only.
// ---------------------------------------------------------------------------
__global__ __launch_bounds__(256) void split_kernel(
    const float* __restrict__ src, unsigned short* __restrict__ dst, int shift)
{
  int idx = blockIdx.x * 256 + threadIdx.x;
  int row = idx >> shift;
  int c4 = idx & ((1 << shift) - 1);
  int Koff = 4 << shift;
  float4 v = ((const float4*)src)[idx];
  ushort4 hi, lo;
  splitf(v.x, &hi.x, &lo.x); splitf(v.y, &hi.y, &lo.y);
  splitf(v.z, &hi.z, &lo.z); splitf(v.w, &hi.w, &lo.w);
  size_t base = ((size_t)row << (shift + 3)) + (size_t)c4 * 4;  // row stride 2K
  *(ushort4*)&dst[base] = hi;
  *(ushort4*)&dst[base + Koff] = lo;
}

// ---------------------------------------------------------------------------
// fp32 -> fp16 elementwise converter (same layout). Used for Wf1/Wf2.
// ---------------------------------------------------------------------------
__global__ __launch_bounds__(256) void tofp16_kernel(
    const float* __restrict__ src, _Float16* __restrict__ dst)
{
  int idx = blockIdx.x * 256 + threadIdx.x;
  float4 v = ((const float4*)src)[idx];
  *(f16x4*)&dst[(size_t)idx * 4] =
      (f16x4){(_Float16)v.x, (_Float16)v.y, (_Float16)v.z, (_Float16)v.w};
}

// ---------------------------------------------------------------------------
// Split-bf16 GEMM: C[M x N] = A[M x K] * W[N x K]^T (+bias)(+relu); A,W stored
// as [hi | lo] bf16 rows (stride 2K).
// chunks=3: virtual K'=3K (A_hi*B_hi + A_lo*B_hi + A_hi*B_lo), ~1e-5 rel.
// chunks=1: hi*hi only (plain bf16 GEMM over the hi halves), ~4e-3 rel.
// m97 structure: 128x128 tile, BK=64, 4 waves, mfma_f32_16x16x32_bf16,
// linear LDS, global_load_lds width 16.
// outmode 0: fp32 C;  outmode 1: split-bf16 C (rows [hi N | lo N], stride 2N);
// outmode 2: plain bf16 C (row stride N).
// All modes offset C by blockIdx.z * czstride (elements); B selected by z.
// ---------------------------------------------------------------------------
__global__ __launch_bounds__(256) void gemm_split(
    const unsigned short* __restrict__ A,
    const unsigned short* __restrict__ B0,
    const unsigned short* __restrict__ B1,
    const unsigned short* __restrict__ B2,
    void* __restrict__ Cbase, long long czstride,
    const float* __restrict__ bias,
    int N, int K, int outmode, int relu, int chunks)
{
  __shared__ unsigned short As[128 * 64];
  __shared__ unsigned short Bs[128 * 64];

  const int tid = threadIdx.x;
  const int lane = tid & 63;
  const int wid = tid >> 6;           // wave 0..3
  const int wr = wid >> 1, wc = wid & 1;
  const int fl = lane & 15;           // fragment row/col
  const int kg = lane >> 4;           // k-group 0..3
  const int z = blockIdx.z;
  const unsigned short* __restrict__ B = (z == 0) ? B0 : ((z == 1) ? B1 : B2);
  const int brow = blockIdx.y * 128;
  const int bcol = blockIdx.x * 128;
  const int ld = 2 * K;

  f32x4 acc[4][4];
#pragma unroll
  for (int i = 0; i < 4; ++i)
#pragma unroll
    for (int j = 0; j < 4; ++j) acc[i][j] = (f32x4){0.f, 0.f, 0.f, 0.f};

  const int r0 = lane >> 3;
  const int c0 = (lane & 7) * 8;

  for (int kt = 0; kt < chunks * K; kt += 64) {
    const int akt = (kt < 2 * K) ? kt : kt - 2 * K;  // hi, lo, hi
    const int bkt = (kt < K) ? kt : kt - K;          // hi, hi, lo
#pragma unroll
    for (int i = 0; i < 4; ++i) {
      const int chunk = i * 4 + wid;                 // 16 chunks of 8 rows
      const int r = chunk * 8 + r0;
      const unsigned short* ga = A + (size_t)(brow + r) * ld + akt + c0;
      const unsigned short* gb = B + (size_t)(bcol + r) * ld + bkt + c0;
      __builtin_amdgcn_global_load_lds(
          (const __attribute__((address_space(1))) void*)ga,
          (__attribute__((address_space(3))) void*)&As[chunk * 512 + lane * 8],
          16, 0, 0);
      __builtin_amdgcn_global_load_lds(
          (const __attribute__((address_space(1))) void*)gb,
          (__attribute__((address_space(3))) void*)&Bs[chunk * 512 + lane * 8],
          16, 0, 0);
    }
    __syncthreads();   // drains vmcnt -> LDS tile ready
#pragma unroll
    for (int kk = 0; kk < 2; ++kk) {
      bf16x8 av[4], bv[4];
#pragma unroll
      for (int f = 0; f < 4; ++f) {
        av[f] = *(const bf16x8*)&As[(wr * 64 + f * 16 + fl) * 64 + kk * 32 + kg * 8];
        bv[f] = *(const bf16x8*)&Bs[(wc * 64 + f * 16 + fl) * 64 + kk * 32 + kg * 8];
      }
#pragma unroll
      for (int i = 0; i < 4; ++i)
#pragma unroll
        for (int j = 0; j < 4; ++j)
          acc[i][j] = __builtin_amdgcn_mfma_f32_16x16x32_bf16(av[i], bv[j], acc[i][j], 0, 0, 0);
    }
    __syncthreads();   // tile consumed before next stage overwrites
  }

  // epilogue — C/D layout: col = lane&15, row = (lane>>4)*4 + reg  [m89]
  if (outmode == 0) {
    float* C = (float*)Cbase + (size_t)z * czstride;
#pragma unroll
    for (int j = 0; j < 4; ++j) {
      const int col = bcol + wc * 64 + j * 16 + fl;
      const float bb = bias ? bias[col] : 0.f;
#pragma unroll
      for (int i = 0; i < 4; ++i) {
        const int rowb = brow + wr * 64 + i * 16 + kg * 4;
#pragma unroll
        for (int e = 0; e < 4; ++e) {
          float v = acc[i][j][e] + bb;
          if (relu) v = fmaxf(v, 0.f);
          C[(size_t)(rowb + e) * N + col] = v;
        }
      }
    }
  } else if (outmode == 1) {
    unsigned short* C = (unsigned short*)Cbase + (size_t)z * czstride;
#pragma unroll
    for (int j = 0; j < 4; ++j) {
      const int col = bcol + wc * 64 + j * 16 + fl;
      const float bb = bias ? bias[col] : 0.f;
#pragma unroll
      for (int i = 0; i < 4; ++i) {
        const int rowb = brow + wr * 64 + i * 16 + kg * 4;
#pragma unroll
        for (int e = 0; e < 4; ++e) {
          float v = acc[i][j][e] + bb;
          if (relu) v = fmaxf(v, 0.f);
          unsigned short hi, lo;
          splitf(v, &hi, &lo);
          size_t rb = (size_t)(rowb + e) * (2 * (size_t)N);
          C[rb + col] = hi;
          C[rb + N + col] = lo;
        }
      }
    }
  } else {
    unsigned short* C = (unsigned short*)Cbase + (size_t)z * czstride;
#pragma unroll
    for (int j = 0; j < 4; ++j) {
      const int col = bcol + wc * 64 + j * 16 + fl;
      const float bb = bias ? bias[col] : 0.f;
#pragma unroll
      for (int i = 0; i < 4; ++i) {
        const int rowb = brow + wr * 64 + i * 16 + kg * 4;
#pragma unroll
        for (int e = 0; e < 4; ++e) {
          float v = acc[i][j][e] + bb;
          if (relu) v = fmaxf(v, 0.f);
          C[(size_t)(rowb + e) * N + col] = f2bf(v);
        }
      }
    }
  }
}

// ---------------------------------------------------------------------------
// Plain-fp16 GEMM: C[M x N] = A[M x K] * W[N x K]^T (+bias)(+relu); A,W fp16
// row-major (ld = K). Single pass, ~1e-3 rel. Used for FFN (round-8 PMC:
// split-3 FFN GEMMs ~500us total = #1 cost; fp16 = 1/3 the MFMA work).
// Same m97 structure. outmode 0: fp32 C; 1: fp16 C.
// ---------------------------------------------------------------------------
__global__ __launch_bounds__(256) void gemm_f16(
    const _Float16* __restrict__ A,
    const _Float16* __restrict__ B,
    void* __restrict__ Cbase,
    const float* __restrict__ bias,
    int N, int K, int outmode, int relu)
{
  __shared__ _Float16 As[128 * 64];
  __shared__ _Float16 Bs[128 * 64];

  const int tid = threadIdx.x;
  const int lane = tid & 63;
  const int wid = tid >> 6;
  const int wr = wid >> 1, wc = wid & 1;
  const int fl = lane & 15;
  const int kg = lane >> 4;
  const int brow = blockIdx.y * 128;
  const int bcol = blockIdx.x * 128;

  f32x4 acc[4][4];
#pragma unroll
  for (int i = 0; i < 4; ++i)
#pragma unroll
    for (int j = 0; j < 4; ++j) acc[i][j] = (f32x4){0.f, 0.f, 0.f, 0.f};

  const int r0 = lane >> 3;
  const int c0 = (lane & 7) * 8;

  for (int kt = 0; kt < K; kt += 64) {
#pragma unroll
    for (int i = 0; i < 4; ++i) {
      const int chunk = i * 4 + wid;
      const int r = chunk * 8 + r0;
      const _Float16* ga = A + (size_t)(brow + r) * K + kt + c0;
      const _Float16* gb = B + (size_t)(bcol + r) * K + kt + c0;
      __builtin_amdgcn_global_load_lds(
          (const __attribute__((address_space(1))) void*)ga,
          (__attribute__((address_space(3))) void*)&As[chunk * 512 + lane * 8],
          16, 0, 0);
      __builtin_amdgcn_global_load_lds(
          (const __attribute__((address_space(1))) void*)gb,
          (__attribute__((address_space(3))) void*)&Bs[chunk * 512 + lane * 8],
          16, 0, 0);
    }
    __syncthreads();
#pragma unroll
    for (int kk = 0; kk < 2; ++kk) {
      f16x8 av[4], bv[4];
#pragma unroll
      for (int f = 0; f < 4; ++f) {
        av[f] = *(const f16x8*)&As[(wr * 64 + f * 16 + fl) * 64 + kk * 32 + kg * 8];
        bv[f] = *(const f16x8*)&Bs[(wc * 64 + f * 16 + fl) * 64 + kk * 32 + kg * 8];
      }
#pragma unroll
      for (int i = 0; i < 4; ++i)
#pragma unroll
        for (int j = 0; j < 4; ++j)
          acc[i][j] = __builtin_amdgcn_mfma_f32_16x16x32_f16(av[i], bv[j], acc[i][j], 0, 0, 0);
    }
    __syncthreads();
  }

  if (outmode == 0) {
    float* C = (float*)Cbase;
#pragma unroll
    for (int j = 0; j < 4; ++j) {
      const int col = bcol + wc * 64 + j * 16 + fl;
      const float bb = bias ? bias[col] : 0.f;
#pragma unroll
      for (int i = 0; i < 4; ++i) {
        const int rowb = brow + wr * 64 + i * 16 + kg * 4;
#pragma unroll
        for (int e = 0; e < 4; ++e) {
          float v = acc[i][j][e] + bb;
          if (relu) v = fmaxf(v, 0.f);
          C[(size_t)(rowb + e) * N + col] = v;
        }
      }
    }
  } else {
    _Float16* C = (_Float16*)Cbase;
#pragma unroll
    for (int j = 0; j < 4; ++j) {
      const int col = bcol + wc * 64 + j * 16 + fl;
      const float bb = bias ? bias[col] : 0.f;
#pragma unroll
      for (int i = 0; i < 4; ++i) {
        const int rowb = brow + wr * 64 + i * 16 + kg * 4;
#pragma unroll
        for (int e = 0; e < 4; ++e) {
          float v = acc[i][j][e] + bb;
          if (relu) v = fmaxf(v, 0.f);
          C[(size_t)(rowb + e) * N + col] = (_Float16)v;
        }
      }
    }
  }
}

// ---------------------------------------------------------------------------
// MFMA flash attention v5: 16 q-rows/wave (was 32) -> 4096 waves = 4/SIMD.
// Round-8 PMC: 151us, Occ 19% (2 waves/SIMD), VALUBusy 45% -> chain half-
// hidden; wave count was pinned by 32 rows/wave. v5 halves rows/wave (drops
// the rg dimension) doubling TLP; per-row math, op order, numerics are
// IDENTICAL to v4 (passing, absmax 0.0156). Block = 4 waves x 16 rows = 64
// q-rows; grid.x = SEQ/64. VGPR ~75 (v4: 92), fits 4 waves/SIMD (<=128).
// K frags double-buffered (T14), V issued at tile top. No barriers.
// ---------------------------------------------------------------------------
__global__ __launch_bounds__(256, 4) void attn_mfma(
    const unsigned short* __restrict__ q2,
    const unsigned short* __restrict__ k2,
    const unsigned short* __restrict__ v2t,
    const int* __restrict__ maskg,
    unsigned short* __restrict__ o2)
{
  __shared__ unsigned short Ps[64 * 40];   // [q-row][32 bf16 P | pad]

  const int tid = threadIdx.x;
  const int lane = tid & 63;
  const int wid = tid >> 6;
  const int fl = lane & 15;
  const int kg = lane >> 4;
  const int b = blockIdx.y >> 3, h = blockIdx.y & 7;
  const int hc = h * 64;
  const int q0w = blockIdx.x * 64 + wid * 16;    // this wave's 16 q-rows
  const float inv_scale = 0.022097086912079608f; // 1/sqrt(2048)
  const size_t bS = (size_t)b * SEQ;

  // hoisted Q fragments (rows q0w+fl): {d0-32, d32-64}
  bf16x8 aq[2];
  {
    size_t qr = (bS + q0w + fl) * 512 + hc + kg * 8;
    aq[0] = *(const bf16x8*)&q2[qr];
    aq[1] = *(const bf16x8*)&q2[qr + 32];
  }

  // per-lane K/V fragment base pointers
  const unsigned short* kp0 = k2 + (bS + fl) * 512 + hc + kg * 8;       // cf=0
  const unsigned short* kp1 = k2 + (bS + 16 + fl) * 512 + hc + kg * 8;  // cf=1
  const unsigned short* vbp[4];
#pragma unroll
  for (int cf = 0; cf < 4; ++cf)
    vbp[cf] = v2t + (size_t)(hc + cf * 16 + fl) * 8192 + bS + kg * 8;
  const int* mrow = maskg + bS;

  float m[4], l[4];
  f32x4 ov[4];
#pragma unroll
  for (int e = 0; e < 4; ++e) { m[e] = -INFINITY; l[e] = 0.f; }
#pragma unroll
  for (int cf = 0; cf < 4; ++cf) ov[cf] = (f32x4){0.f, 0.f, 0.f, 0.f};

  // unique K frags per tile: {d0-32, d32-64} x {key grp 0,1}
  auto ldk = [&](bf16x8 (&kf)[4], int k0) {
    size_t kr = (size_t)k0 * 512;
    kf[0] = *(const bf16x8*)(kp0 + kr);
    kf[1] = *(const bf16x8*)(kp0 + kr + 32);
    kf[2] = *(const bf16x8*)(kp1 + kr);
    kf[3] = *(const bf16x8*)(kp1 + kr + 32);
  };
  // unique V frags per tile: 4 cf
  auto ldv = [&](bf16x8 (&vf)[4], int k0) {
#pragma unroll
    for (int cf = 0; cf < 4; ++cf)
      vf[cf] = *(const bf16x8*)(vbp[cf] + k0);
  };

  auto tile = [&](const bf16x8 (&kf)[4], const bf16x8 (&vf)[4], int k0) {
    const bool dead0 = (mrow[k0 + fl] == 0);
    const bool dead1 = (mrow[k0 + 16 + fl] == 0);

    // ---- QK^T: 2 d-chunks x 2 col-frags = 4 MFMA ----
    f32x4 sc[2];
    sc[0] = (f32x4){0.f, 0.f, 0.f, 0.f};
    sc[1] = (f32x4){0.f, 0.f, 0.f, 0.f};
#pragma unroll
    for (int c = 0; c < 2; ++c) {
      sc[0] = __builtin_amdgcn_mfma_f32_16x16x32_bf16(aq[c], kf[c], sc[0], 0, 0, 0);
      sc[1] = __builtin_amdgcn_mfma_f32_16x16x32_bf16(aq[c], kf[2 + c], sc[1], 0, 0, 0);
    }

    // ---- mask + scale + online softmax (lane rows = kg*4+e) ----
#pragma unroll
    for (int e = 0; e < 4; ++e) {
      float s0 = dead0 ? -1e20f : sc[0][e];
      float s1 = dead1 ? -1e20f : sc[1][e];
      sc[0][e] = s0 * inv_scale;
      sc[1][e] = s1 * inv_scale;
    }
#pragma unroll
    for (int e = 0; e < 4; ++e) {
      float rm = fmaxf(sc[0][e], sc[1][e]);
      rm = fmaxf(rm, __shfl_xor(rm, 1));
      rm = fmaxf(rm, __shfl_xor(rm, 2));
      rm = fmaxf(rm, __shfl_xor(rm, 4));
      rm = fmaxf(rm, __shfl_xor(rm, 8));
      float mnew = fmaxf(m[e], rm);
      float corr = __expf(m[e] - mnew);   // first tile: exp(-inf)=0
      float p0 = __expf(sc[0][e] - mnew);
      float p1 = __expf(sc[1][e] - mnew);
      sc[0][e] = p0; sc[1][e] = p1;
      float ps = p0 + p1;
      ps += __shfl_xor(ps, 1); ps += __shfl_xor(ps, 2);
      ps += __shfl_xor(ps, 4); ps += __shfl_xor(ps, 8);
      l[e] = l[e] * corr + ps;
      m[e] = mnew;
#pragma unroll
      for (int cf = 0; cf < 4; ++cf) ov[cf][e] *= corr;
    }
    // P -> LDS, plain bf16 (wave-exclusive rows; same-wave RAW, no barrier)
#pragma unroll
    for (int cf = 0; cf < 2; ++cf)
#pragma unroll
      for (int e = 0; e < 4; ++e) {
        int prow = wid * 16 + kg * 4 + e;
        Ps[prow * 40 + cf * 16 + fl] = f2bf(sc[cf][e]);
      }

    // ---- O += P @ V: 4 MFMA ----
    bf16x8 ap = *(const bf16x8*)&Ps[(wid * 16 + fl) * 40 + kg * 8];
#pragma unroll
    for (int cf = 0; cf < 4; ++cf)
      ov[cf] = __builtin_amdgcn_mfma_f32_16x16x32_bf16(ap, vf[cf], ov[cf], 0, 0, 0);
  };

  // ---- software-pipelined main loop (x2 unroll, named A/B buffers) ----
  bf16x8 ka[4], kb[4], va[4], vc[4];
  ldk(ka, 0);
  for (int k0 = 0; k0 < SEQ; k0 += 64) {
    ldv(va, k0);           // V(t) in flight under QK+softmax(t)
    ldk(kb, k0 + 32);      // K(t+1) in flight under all of tile t
    tile(ka, va, k0);
    ldv(vc, k0 + 32);
    ldk(ka, k0 + 64);      // last iter: harmless overrun into v2t, unused
    tile(kb, vc, k0 + 32);
  }

  // ---- epilogue: O/l -> split-bf16 into act2 (Wo input precision kept) ----
#pragma unroll
  for (int e = 0; e < 4; ++e) {
    float inv = 1.0f / l[e];
    size_t trow = (bS + q0w + kg * 4 + e) * 1024 + hc;
#pragma unroll
    for (int cf = 0; cf < 4; ++cf) {
      float v = ov[cf][e] * inv;
      unsigned short hi = f2bf(v);
      unsigned short lo = f2bf(v - bf2f(hi));
      o2[trow + cf * 16 + fl] = hi;
      o2[trow + 512 + cf * 16 + fl] = lo;
    }
  }
}

// ---------------------------------------------------------------------------
// Fused residual + LayerNorm: out = LN(X + R) * g + b; optionally emits
// split-bf16 copy (out2, row stride 2*EDIM) and/or fp16 copy (outh, stride E).
// ---------------------------------------------------------------------------
__global__ __launch_bounds__(128) void ln_res_kernel(
    const float* __restrict__ X, const float* __restrict__ R,
    const float* __restrict__ g, const float* __restrict__ be,
    float* __restrict__ out, unsigned short* __restrict__ out2,
    _Float16* __restrict__ outh)
{
  const int row = blockIdx.x;
  const int tid = threadIdx.x;
  const long long off = (long long)row * EDIM + tid * 4;
  float4 xv = *(const float4*)&X[off];
  float4 rv = *(const float4*)&R[off];
  float x0 = xv.x + rv.x, x1 = xv.y + rv.y, x2 = xv.z + rv.z, x3 = xv.w + rv.w;

  __shared__ float red[2];
  float s = (x0 + x1) + (x2 + x3);
#pragma unroll
  for (int o2 = 1; o2 < 64; o2 <<= 1) s += __shfl_xor(s, o2);
  if ((tid & 63) == 0) red[tid >> 6] = s;
  __syncthreads();
  float mean = (red[0] + red[1]) * (1.0f / EDIM);

  float d0 = x0 - mean, d1 = x1 - mean, d2 = x2 - mean, d3 = x3 - mean;
  float s2 = (d0 * d0 + d1 * d1) + (d2 * d2 + d3 * d3);
#pragma unroll
  for (int o2 = 1; o2 < 64; o2 <<= 1) s2 += __shfl_xor(s2, o2);
  __syncthreads();
  if ((tid & 63) == 0) red[tid >> 6] = s2;
  __syncthreads();
  float var = (red[0] + red[1]) * (1.0f / EDIM);
  float rstd = rsqrtf(var + 1e-5f);

  float4 gv = *(const float4*)&g[tid * 4];
  float4 bv = *(const float4*)&be[tid * 4];
  float4 ov;
  ov.x = d0 * rstd * gv.x + bv.x;
  ov.y = d1 * rstd * gv.y + bv.y;
  ov.z = d2 * rstd * gv.z + bv.z;
  ov.w = d3 * rstd * gv.w + bv.w;
  *(float4*)&out[off] = ov;

  if (out2) {
    ushort4 hi, lo;
    splitf(ov.x, &hi.x, &lo.x); splitf(ov.y, &hi.y, &lo.y);
    splitf(ov.z, &hi.z, &lo.z); splitf(ov.w, &hi.w, &lo.w);
    size_t b2 = ((size_t)row << 10) + (size_t)tid * 4;
    *(ushort4*)&out2[b2] = hi;
    *(ushort4*)&out2[b2 + EDIM] = lo;
  }
  if (outh) {
    *(f16x4*)&outh[(size_t)row * EDIM + tid * 4] =
        (f16x4){(_Float16)ov.x, (_Float16)ov.y, (_Float16)ov.z, (_Float16)ov.w};
  }
}

// ---------------------------------------------------------------------------
extern "C" void kernel_launch(void* const* d_in, const int* in_sizes, int n_in,
                              void* d_out, int out_size, void* d_ws, size_t ws_size,
                              hipStream_t stream) {
  (void)in_sizes; (void)n_in; (void)out_size; (void)ws_size;

  const int*   x    = (const int*)d_in[0];
  const int*   mask = (const int*)d_in[1];
  const float* emb  = (const float*)d_in[2];
  const float* pos  = (const float*)d_in[3];
  const float* Wq   = (const float*)d_in[4];
  const float* Wk   = (const float*)d_in[5];
  const float* Wv   = (const float*)d_in[6];
  const float* Wo   = (const float*)d_in[7];
  const float* bo   = (const float*)d_in[8];
  const float* ln1g = (const float*)d_in[9];
  const float* ln1b = (const float*)d_in[10];
  const float* ln2g = (const float*)d_in[11];
  const float* ln2b = (const float*)d_in[12];
  const float* Wf1  = (const float*)d_in[13];
  const float* bf1  = (const float*)d_in[14];
  const float* Wf2  = (const float*)d_in[15];
  const float* bf2  = (const float*)d_in[16];
  float* out = (float*)d_out;

  // ws layout (float units):
  //   hb [0,MEL) | h1 [MEL,2MEL)
  //   q2 [2,2.5)MEL  k2 [2.5,3)MEL  v2t [3,3.5)MEL   (bf16, attn inputs)
  //   t1 aliases [2,3)MEL (fp32 Wo out, q2/k2 dead)
  //   h1f [3.5,4)MEL (fp16 LN1 out)   ff1h [4,6)MEL (fp16 FF1 out)
  //   act2 [6,7)MEL (split bf16) | weight converts after
  float* hb = (float*)d_ws;
  float* h1 = hb + MEL;
  unsigned short* q2  = (unsigned short*)(hb + 2 * MEL);
  unsigned short* k2  = q2 + (size_t)MTOK * 512;
  unsigned short* v2t = k2 + (size_t)MTOK * 512;    // [512 n][8192 tok]
  float* t1 = (float*)(hb + 2 * MEL);               // alias q2+k2 (dead post-attn)
  _Float16* h1f  = (_Float16*)(hb + 3 * MEL + MEL / 2);
  _Float16* ff1h = (_Float16*)(hb + 4 * MEL);       // M x 2048 fp16
  unsigned short* act2 = (unsigned short*)(hb + 6 * MEL); // M x 1024
  unsigned short* wq2  = act2 + (size_t)MTOK * 1024;      // 512 x 1024 each
  unsigned short* wk2  = wq2 + 512 * 1024;
  unsigned short* wv2  = wk2 + 512 * 1024;
  unsigned short* wo2  = wv2 + 512 * 1024;
  unsigned short* wf12 = wo2 + 512 * 1024;                // reused as fp16 Wf1
  unsigned short* wf22 = wf12 + (size_t)2048 * 1024;      // reused as fp16 Wf2
  _Float16* wf1h = (_Float16*)wf12;                 // 2048 x 512 fp16
  _Float16* wf2h = (_Float16*)wf22;                 // 512 x 2048 fp16

  embed_kernel<<<dim3(MTOK * (EDIM / 4) / 256), 256, 0, stream>>>(x, emb, pos, hb, act2);

  for (int l = 0; l < NLAYER; ++l) {
    const float* wq = Wq + (long long)l * EDIM * EDIM;
    const float* wk = Wk + (long long)l * EDIM * EDIM;
    const float* wv = Wv + (long long)l * EDIM * EDIM;
    const float* wo = Wo + (long long)l * EDIM * EDIM;
    const float* wf1 = Wf1 + (long long)l * FFD * EDIM;
    const float* wf2 = Wf2 + (long long)l * EDIM * FFD;

    // weight converts: QKV/Wo split-bf16; Wf1/Wf2 fp16
    split_kernel<<<dim3(256), 256, 0, stream>>>(wq, wq2, 7);      // 512 x 512
    split_kernel<<<dim3(256), 256, 0, stream>>>(wk, wk2, 7);
    split_kernel<<<dim3(256), 256, 0, stream>>>(wv, wv2, 7);
    split_kernel<<<dim3(256), 256, 0, stream>>>(wo, wo2, 7);
    tofp16_kernel<<<dim3(1024), 256, 0, stream>>>(wf1, wf1h);     // 2048 x 512
    tofp16_kernel<<<dim3(1024), 256, 0, stream>>>(wf2, wf2h);     // 512 x 2048

    // Q,K projections: hi-only bf16 GEMM (chunks=1), plain bf16 out
    gemm_split<<<dim3(EDIM / 128, MTOK / 128, 2), 256, 0, stream>>>(
        act2, wq2, wk2, nullptr, q2, (long long)MTOK * 512, nullptr,
        EDIM, EDIM, 2, 0, 1);

    // V projection, SWAPPED operands -> V^T [n][token], bf16 out, hi-only
    gemm_split<<<dim3(MTOK / 128, EDIM / 128, 1), 256, 0, stream>>>(
        wv2, act2, nullptr, nullptr, v2t, 0, nullptr,
        MTOK, EDIM, 2, 0, 1);

    // flash attention v5 (16 rows/wave, 4 waves/SIMD)
    attn_mfma<<<dim3(SEQ / 64, BATCH * NH), 256, 0, stream>>>(
        q2, k2, v2t, mask, act2);

    // output projection (+bo), full split precision, fp32 out
    gemm_split<<<dim3(EDIM / 128, MTOK / 128, 1), 256, 0, stream>>>(
        act2, wo2, nullptr, nullptr, t1, 0, bo + (long long)l * EDIM,
        EDIM, EDIM, 0, 0, 3);

    // h1 = LN(t1 + h), emit fp16 h1 for the fp16 FFN
    ln_res_kernel<<<MTOK, 128, 0, stream>>>(
        t1, hb, ln1g + (long long)l * EDIM, ln1b + (long long)l * EDIM,
        h1, nullptr, h1f);

    // ff = relu(h1 @ Wf1^T + bf1), fp16 single-pass, fp16 out
    gemm_f16<<<dim3(FFD / 128, MTOK / 128), 256, 0, stream>>>(
        h1f, wf1h, ff1h, bf1 + (long long)l * FFD, FFD, EDIM, 1, 1);

    // ff @ Wf2^T + bf2, fp16 single-pass, fp32 out -> hb
    gemm_f16<<<dim3(EDIM / 128, MTOK / 128), 256, 0, stream>>>(
        ff1h, wf2h, hb, bf2 + (long long)l * EDIM, EDIM, FFD, 0, 0);

    // h = LN(hb + h1); final layer -> d_out
    float* lnout = (l == NLAYER - 1) ? out : hb;
    unsigned short* lnout2 = (l == NLAYER - 1) ? nullptr : act2;
    ln_res_kernel<<<MTOK, 128, 0, stream>>>(
        hb, h1, ln2g + (long long)l * EDIM, ln2b + (long long)l * EDIM,
        lnout, lnout2, nullptr);
  }
}